// Round 10
// baseline (3276.842 us; speedup 1.0000x reference)
//
#include <hip/hip_runtime.h>
#include <hip/hip_bf16.h>
#include <cstdint>

#define SEQL 3136

typedef __attribute__((ext_vector_type(8))) short v8s;
typedef __attribute__((ext_vector_type(4))) float f32x4;
typedef __attribute__((ext_vector_type(4))) int v4i;

__device__ __forceinline__ uint16_t bf16u(float f) {
    uint32_t u = __float_as_uint(f);
    uint32_t r = u + 0x7fff + ((u >> 16) & 1);   // RNE
    return (uint16_t)(r >> 16);
}
__device__ __forceinline__ float bf2f(uint16_t b) {
    uint32_t u = ((uint32_t)b) << 16;
    return __uint_as_float(u);
}

// ---------------- merged prep: bf16 weight cvt + conv sign-weight fragment buffers ---
// W2I: conv2 i8 B-fragments, byte = ((r147*2 + nt)*64 + lane)*16 + s (lane-major,
// coalesced). W1F: conv1 bf16 B-fragments, u16 idx = (((kw*4+ks*2+wn)*2+f)*64+lane)*8+e
// with oc = wn*32 + f*16 + (lane&15), c = ks*32 + (lane>>4)*8 + e  (lane-major).
__global__ __launch_bounds__(256) void k_prep(const float* __restrict__ qw,
                                              const float* __restrict__ pw,
                                              const float* __restrict__ f1,
                                              const float* __restrict__ f2,
                                              const float* __restrict__ w1,
                                              const float* __restrict__ w2,
                                              const float* __restrict__ w3,
                                              uint16_t* __restrict__ dq,
                                              uint16_t* __restrict__ dp,
                                              uint16_t* __restrict__ d1,
                                              uint16_t* __restrict__ d2,
                                              uint16_t* __restrict__ w1b,
                                              uint64_t* __restrict__ wp2,
                                              uint64_t* __restrict__ wn2,
                                              uint32_t* __restrict__ wp3,
                                              uint32_t* __restrict__ wn3,
                                              uint32_t* __restrict__ w2i,
                                              uint16_t* __restrict__ w1f) {
    int gid = blockIdx.x * 256 + threadIdx.x;
    if (gid < 1376256) { dq[gid] = bf16u(qw[gid]); return; }
    if (gid < 1835008) { int i = gid - 1376256; dp[i] = bf16u(pw[i]); return; }
    if (gid < 2752512) { int i = gid - 1835008; d1[i] = bf16u(f1[i]); return; }
    if (gid < 3670016) { int i = gid - 2752512; d2[i] = bf16u(f2[i]); return; }
    if (gid < 3698688) {
        // conv1 sign weights as bf16: W1B[kw][oc][c=(ic*3+kd)*7+kh], c=63 -> 0 (legacy)
        int i = gid - 3670016;
        int c = i & 63, oc = (i >> 6) & 63, kw = i >> 12;
        uint16_t v = 0;
        if (c < 63) {
            int ic = c / 21, rem = c % 21, kd = rem / 7, kh = rem % 7;
            float w = w1[((((oc * 3 + ic) * 3 + kd) * 7 + kh) * 7) + kw];
            v = (w > 0.f) ? 0x3F80 : ((w < 0.f) ? 0xBF80 : 0);
        }
        w1b[i] = v;
        return;
    }
    if (gid < 3703392) {
        int i = gid - 3698688;
        int oc = i / 147, r = i % 147;
        uint64_t p = 0, n = 0;
        for (int ic = 0; ic < 64; ic++) {
            float v = w2[(long)oc * 9408 + (long)ic * 147 + r];
            if (v > 0.f) p |= (1ull << ic);
            else if (v < 0.f) n |= (1ull << ic);
        }
        wp2[i] = p; wn2[i] = n;
        return;
    }
    if (gid < 3703833) {
        int i = gid - 3703392;
        int oc = i / 147, r = i % 147;
        uint32_t p = 0, n = 0;
        for (int ic = 0; ic < 32; ic++) {
            float v = w3[(long)oc * 4704 + (long)ic * 147 + r];
            if (v > 0.f) p |= (1u << ic);
            else if (v < 0.f) n |= (1u << ic);
        }
        wp3[i] = p; wn3[i] = n;
        return;
    }
    if (gid < 3779097) {
        // conv2 i8 MFMA B-fragment weights: 75,264 dwords = 301,056 bytes
        int j = gid - 3703833;             // dword index
        int s4 = (j & 3) * 4;              // byte offset within the 16B lane block
        int lane = (j >> 2) & 63;
        int nt = (j >> 8) & 1;
        int r = j >> 9;                    // 0..146 = kd*49 + kh*7 + kw
        int g = lane >> 4, tl = lane & 15;
        int oc = nt * 16 + tl;
        uint32_t out = 0;
        for (int bb = 0; bb < 4; bb++) {
            int ic = g * 16 + s4 + bb;
            float w = w2[(long)oc * 9408 + (long)ic * 147 + r];
            uint32_t s8 = (w > 0.f) ? 0x01u : ((w < 0.f) ? 0xFFu : 0x00u);
            out |= s8 << (8 * bb);
        }
        w2i[j] = out;
        return;
    }
    if (gid < 3807769) {
        // conv1 bf16 MFMA B-fragments, lane-major: 28,672 u16 = 57,344 bytes
        int i = gid - 3779097;
        int e = i & 7;
        int lane = (i >> 3) & 63;
        int f = (i >> 9) & 1;
        int wn = (i >> 10) & 1;
        int ks = (i >> 11) & 1;
        int kw = i >> 12;                  // 0..6
        int tl = lane & 15, g = lane >> 4;
        int oc = wn * 32 + f * 16 + tl;
        int c = ks * 32 + g * 8 + e;
        uint16_t v = 0;
        if (c < 63) {
            int ic = c / 21, rem = c % 21, kd = rem / 7, kh = rem % 7;
            float w = w1[((((oc * 3 + ic) * 3 + kd) * 7 + kh) * 7) + kw];
            v = (w > 0.f) ? 0x3F80 : ((w < 0.f) ? 0xBF80 : 0);
        }
        w1f[i] = v;
    }
}

// ---------------- prepx: 3-way bf16 split of x into padded planes -------------------
// X3[s][b][ic][dslot 27][ih' 232][iw' 232] u16; dslot = d+1 (slot0 = zero plane);
// ih' = ih+3, iw' = iw+3; borders zero. Written as u32 (iw'-pairs).
__global__ __launch_bounds__(256) void k_prepx(const float* __restrict__ x,
                                               uint32_t* __restrict__ X3) {
    int gid = blockIdx.x * 256 + threadIdx.x;
    if (gid >= 26158464) return;
    int iwp = gid % 116;
    int t = gid / 116;
    int ihp = t % 232; t /= 232;
    int dslot = t % 27; t /= 27;
    int ic = t % 3; t /= 3;
    int b = t & 3; int s = t >> 2;
    int d = dslot - 1;
    int ih = ihp - 3;
    uint32_t out = 0;
    if (d >= 0 && (unsigned)ih < 224u) {
        const float* xp = x + ((long)(b * 3 + ic) * 27 + d) * 50176 + ih * 224;
#pragma unroll
        for (int half = 0; half < 2; half++) {
            int iw = 2 * iwp + half - 3;
            float v = ((unsigned)iw < 224u) ? xp[iw] : 0.f;
            uint16_t hi = bf16u(v);
            uint16_t o = hi;
            if (s > 0) {
                float r1 = v - bf2f(hi);
                uint16_t lo = bf16u(r1);
                o = (s == 2) ? bf16u(r1 - bf2f(lo)) : lo;
            }
            out |= ((uint32_t)o) << (16 * half);
        }
    }
    X3[gid] = out;
}

// ---------------- conv1: MFMA implicit GEMM from pre-split X3, packed u64 out --------
// block = (oh, od, b). M=224 ow (14 tiles), N=64 oc (4 tiles), K = 7kw x 64c x 3splits.
// Weights: double-buffered LDS staging of W1F (lane-major, conflict-free ds_read_b128),
// prefetch kw+1 before computing kw; 1 barrier per kw. obits16 aliases Wb[1] (dead in
// epilogue) -> 51.6 KB LDS. oh XCD-swizzled for L2 row reuse (FETCH 357->60MB, r9).
// NOTE: register-staged Xt pipeline (r8) spilled to scratch (WRITE_SIZE 14MB->908MB,
// VGPR 116->84) and regressed 2x — do not reintroduce without verifying no localMem.
__device__ __forceinline__ v8s ldA76(const uint16_t* Xt, int colb, int c0) {
    union { v8s v; uint2 u[2]; } t;
    const uint16_t* p = Xt + colb * 76 + c0;
    t.u[0] = *(const uint2*)p;
    t.u[1] = *(const uint2*)(p + 4);
    return t.v;
}

__global__ __launch_bounds__(256) void k_conv1m(const uint16_t* __restrict__ X3,
                                                const uint16_t* __restrict__ w1f,
                                                uint64_t* __restrict__ b1p) {
    __shared__ __align__(16) uint16_t Xt[232 * 76];   // [col][c] stride 76 (38dw, gcd2)
    __shared__ __align__(16) uint16_t Wb[2][4096];    // dbuf weights; Wb[1] = obits alias
    int tid = threadIdx.x;
    int bidx = blockIdx.x;
    int oh = (bidx & 7) * 28 + (bidx >> 3);           // XCD-contiguous oh (224 = 8*28)
    int od = blockIdx.y, b = blockIdx.z;
    int lane = tid & 63, wv = tid >> 6;
    int wm = wv >> 1, wn = wv & 1;
    int tl = lane & 15, g = lane >> 4;

    f32x4 acc[7][2];
#pragma unroll
    for (int mt = 0; mt < 7; mt++) {
        acc[mt][0] = (f32x4){0.f, 0.f, 0.f, 0.f};
        acc[mt][1] = (f32x4){0.f, 0.f, 0.f, 0.f};
    }

    for (int s = 0; s < 3; s++) {
        // Xt/Wb[0] writable: s=0 nothing read yet; s>0 covered by final kw barrier of s-1.
        if (tid < 232) {
            // base: (s,b) block + od plane group + oh row + col
            const uint16_t* Xb = X3 + ((long)(s * 4 + b) * 81 + (long)od * 3) * 53824
                               + oh * 232 + tid;
#pragma unroll
            for (int cp = 0; cp < 32; cp++) {
                const int c0 = 2 * cp, c1 = c0 + 1;
                uint32_t v0 = 0, v1 = 0;
                if (c0 < 63) {
                    const int ickd = c0 / 7, kh = c0 % 7;
                    const int ic = ickd / 3, kd = ickd % 3;
                    v0 = Xb[(long)(ic * 27 + kd) * 53824 + kh * 232];
                }
                if (c1 < 63) {
                    const int ickd = c1 / 7, kh = c1 % 7;
                    const int ic = ickd / 3, kd = ickd % 3;
                    v1 = Xb[(long)(ic * 27 + kd) * 53824 + kh * 232];
                }
                *(uint32_t*)&Xt[tid * 76 + c0] = v0 | (v1 << 16);
            }
        }
        {   // stage kw=0 weights into Wb[0] (8 KB, coalesced uint4)
            const uint4* src = (const uint4*)w1f;
            uint4* dst = (uint4*)Wb[0];
            dst[tid] = src[tid];
            dst[256 + tid] = src[256 + tid];
        }
        __syncthreads();   // Xt + Wb[0] visible
        for (int kw = 0; kw < 7; kw++) {
            int cur = kw & 1;
            if (kw < 6) {
                // prefetch kw+1 into the other buffer; latency hides under MFMAs
                const uint4* src = (const uint4*)(w1f + (kw + 1) * 4096);
                uint4* dst = (uint4*)Wb[cur ^ 1];
                dst[tid] = src[tid];
                dst[256 + tid] = src[256 + tid];
            }
#pragma unroll
            for (int ks = 0; ks < 2; ks++) {
                // lane-major: ds_read_b128 at lane*16, conflict-free
                const uint16_t* wfb = &Wb[cur][((ks * 2 + wn) * 2) * 512 + lane * 8];
                v8s b0 = *(const v8s*)wfb;
                v8s b1 = *(const v8s*)(wfb + 512);
#pragma unroll
                for (int mt = 0; mt < 7; mt++) {
                    int colb = (wm * 7 + mt) * 16 + tl + kw;   // Xt index = xcol+3
                    v8s a = ldA76(Xt, colb, ks * 32 + g * 8);
                    acc[mt][0] = __builtin_amdgcn_mfma_f32_16x16x32_bf16(a, b0, acc[mt][0], 0, 0, 0);
                    acc[mt][1] = __builtin_amdgcn_mfma_f32_16x16x32_bf16(a, b1, acc[mt][1], 0, 0, 0);
                }
            }
            __syncthreads();   // Wb[cur^1] written+visible; Wb[cur] reads done
        }
    }
    // epilogue: ballot -> 16-bit oc pieces (obits aliases Wb[1]; all Wb reads done)
    uint16_t* obits16 = (uint16_t*)Wb[1];
#pragma unroll
    for (int mt = 0; mt < 7; mt++)
#pragma unroll
        for (int nt = 0; nt < 2; nt++)
#pragma unroll
            for (int r = 0; r < 4; r++) {
                unsigned long long mask = __ballot(acc[mt][nt][r] > 0.f);
                if (tl == 0) {
                    int ow = (wm * 7 + mt) * 16 + g * 4 + r;
                    obits16[ow * 4 + wn * 2 + nt] = (uint16_t)(mask >> (g * 16));
                }
            }
    __syncthreads();
    if (tid < 224) {
        uint64_t w = (uint64_t)obits16[tid * 4]
                   | ((uint64_t)obits16[tid * 4 + 1] << 16)
                   | ((uint64_t)obits16[tid * 4 + 2] << 32)
                   | ((uint64_t)obits16[tid * 4 + 3] << 48);
        b1p[(((long)b * 9 + od) * 224 + oh) * 224 + tid] = w;
    }
}

// ---------------- conv2: i8 MFMA implicit GEMM over packed bitplanes -----------------
// block = (oh, od, b). M = 224 ow (14 tiles, interleaved across waves), N = 32 oc
// (2 tiles, both per wave), K = 147 taps x 64 ic; one 16x16x64 i8 MFMA per tap.
// A built in-register: 16 ic bits -> 16 i8 {0,1} via nibble magic-multiply spread.
// Weights read directly from L2 (w2i fragment-ordered); oh XCD-swizzled for B1P reuse.
__global__ __launch_bounds__(256) void k_conv2m(const uint64_t* __restrict__ bp1,
                                                const uint8_t* __restrict__ w2i,
                                                uint32_t* __restrict__ b2p) {
    __shared__ __align__(16) uint64_t xs[21 * 232];       // 38,976 B  packed input rows
    __shared__ uint16_t obits16[224 * 2];
    int tid = threadIdx.x;
    int bidx = blockIdx.x;
    int oh = (bidx & 7) * 28 + (bidx >> 3);               // XCD-contiguous oh
    int od = blockIdx.y, b = blockIdx.z;
    int lane = tid & 63, wv = tid >> 6;
    int tl = lane & 15, g = lane >> 4;
    int g2 = g >> 1, sh = (g & 1) * 16;

    // stage all 21 (kd,kh) rows of packed u64 bits, zero-padded borders
    for (int i = tid; i < 21 * 232; i += 256) {
        int row = i / 232, wp = i - row * 232;
        int kd = row / 7, kh = row - kd * 7;
        int d = od * 3 - 1 + kd;
        int h = oh - 3 + kh;
        int w = wp - 3;
        uint64_t v = 0;
        if ((unsigned)d < 9u && (unsigned)h < 224u && (unsigned)w < 224u)
            v = bp1[(((long)b * 9 + d) * 224 + h) * 224 + w];
        xs[i] = v;
    }

    int nmt = (wv < 2) ? 4 : 3;   // waves 0,1: 4 M-tiles; waves 2,3: 3 M-tiles
    v4i acc[4][2];
#pragma unroll
    for (int mi = 0; mi < 4; mi++) {
        acc[mi][0] = (v4i){0, 0, 0, 0};
        acc[mi][1] = (v4i){0, 0, 0, 0};
    }
    __syncthreads();   // xs visible

    for (int row = 0; row < 21; row++) {
        const uint8_t* wr = w2i + (long)row * 14336;      // L2-resident fragments
        const uint32_t* x32 = (const uint32_t*)&xs[row * 232];
#pragma unroll
        for (int kw = 0; kw < 7; kw++) {
            v4i bf0 = *(const v4i*)&wr[(kw * 2 + 0) * 1024 + lane * 16];
            v4i bf1 = *(const v4i*)&wr[(kw * 2 + 1) * 1024 + lane * 16];
#pragma unroll
            for (int mi = 0; mi < 4; mi++) {
                if (mi < nmt) {
                    int mt = wv + mi * 4;
                    // 16 ic bits for this lane's k-chunk (g*16..+15) at position ow+kw
                    uint32_t c = x32[(mt * 16 + tl + kw) * 2 + g2] >> sh;
                    v4i a;
#pragma unroll
                    for (int j = 0; j < 4; j++) {
                        uint32_t d4 = (c >> (4 * j)) & 0xFu;
                        a[j] = (int)((d4 * 0x204081u) & 0x01010101u);
                    }
                    acc[mi][0] = __builtin_amdgcn_mfma_i32_16x16x64_i8(a, bf0, acc[mi][0], 0, 0, 0);
                    acc[mi][1] = __builtin_amdgcn_mfma_i32_16x16x64_i8(a, bf1, acc[mi][1], 0, 0, 0);
                }
            }
        }
    }
    // epilogue: sign bits via ballot, pack 32 oc bits per ow
#pragma unroll
    for (int mi = 0; mi < 4; mi++) {
        if (mi < nmt) {
            int mt = wv + mi * 4;
#pragma unroll
            for (int nt = 0; nt < 2; nt++)
#pragma unroll
                for (int r = 0; r < 4; r++) {
                    unsigned long long mask = __ballot(acc[mi][nt][r] > 0);
                    if (tl == 0)
                        obits16[(mt * 16 + g * 4 + r) * 2 + nt] = (uint16_t)(mask >> (g * 16));
                }
        }
    }
    __syncthreads();
    if (tid < 224) {
        uint32_t wo = (uint32_t)obits16[tid * 2] | ((uint32_t)obits16[tid * 2 + 1] << 16);
        b2p[(((long)b * 3 + od) * 224 + oh) * 224 + tid] = wo;
    }
}

// conv3 via popcount -> fp32 relu count
__global__ __launch_bounds__(256) void k_conv3(const uint32_t* __restrict__ bp2,
                                               const uint32_t* __restrict__ wp,
                                               const uint32_t* __restrict__ wn,
                                               float* __restrict__ h3) {
    int gid = blockIdx.x * 256 + threadIdx.x;  // 602,112
    int q = gid;
    int ow = q % 224; q /= 224;
    int oh = q % 224; q /= 224;
    int oc = q % 3;   int b = q / 3;
    int acc = 0;
    for (int kd = 0; kd < 3; kd++) {
        int d = kd - 1;
        if ((unsigned)d >= 3u) continue;
        for (int kh = 0; kh < 7; kh++) {
            int h = oh - 3 + kh;
            if ((unsigned)h >= 224u) continue;
            const uint32_t* bp = bp2 + ((long)(b * 3 + d) * 224 + h) * 224;
            const uint32_t* mp = wp + ((oc * 3 + kd) * 7 + kh) * 7;
            const uint32_t* mn = wn + ((oc * 3 + kd) * 7 + kh) * 7;
#pragma unroll
            for (int kw = 0; kw < 7; kw++) {
                int w = ow - 3 + kw;
                if ((unsigned)w < 224u) {
                    uint32_t bits = bp[w];
                    acc += __popc(bits & mp[kw]) - __popc(bits & mn[kw]);
                }
            }
        }
    }
    h3[gid] = fmaxf((float)acc, 0.f);
}

// ---------------- tokenizer conv; tok layout [b][h][w][c] ----------------
__global__ __launch_bounds__(256) void k_tok(const float* __restrict__ h3,
                                             const float* __restrict__ wt,
                                             float* __restrict__ tok) {
    __shared__ float xs[3 * 7 * 232];
    int tid = threadIdx.x;
    int oh = blockIdx.x, b = blockIdx.y;
    for (int i = tid; i < 3 * 7 * 232; i += 256) {
        int col = i % 232; int t = i / 232;
        int kh = t % 7; int ic = t / 7;
        int ih = oh * 2 - 3 + kh;
        int iw = col - 3;
        float v = 0.f;
        if ((unsigned)ih < 224u && (unsigned)iw < 224u)
            v = h3[((long)(b * 3 + ic) * 50176) + ih * 224 + iw];
        xs[i] = v;
    }
    __syncthreads();
    int oc = tid;
    float* obase = tok + ((long)(b * 112 + oh) * 112) * 256 + oc;
    for (int chunk = 0; chunk < 4; chunk++) {
        int ow0 = chunk * 28;
        float acc[28];
#pragma unroll
        for (int o2 = 0; o2 < 28; o2++) acc[o2] = 0.f;
        for (int ic = 0; ic < 3; ic++) {
#pragma unroll
            for (int kh = 0; kh < 7; kh++) {
                const float* row = &xs[(ic * 7 + kh) * 232 + ow0 * 2];
                float xv[61];
#pragma unroll
                for (int t = 0; t < 61; t++) xv[t] = row[t];
                const float* wr = wt + (oc * 3 + ic) * 49 + kh * 7;
                float w[7];
#pragma unroll
                for (int kw = 0; kw < 7; kw++) w[kw] = wr[kw];
#pragma unroll
                for (int kw = 0; kw < 7; kw++)
#pragma unroll
                    for (int o2 = 0; o2 < 28; o2++)
                        acc[o2] = fmaf(w[kw], xv[2 * o2 + kw], acc[o2]);
            }
        }
#pragma unroll
        for (int o2 = 0; o2 < 28; o2++)
            obase[(long)(ow0 + o2) * 256] = fmaxf(acc[o2], 0.f);
    }
}

// maxpool 3x3 s2 p1 + pos_emb
__global__ __launch_bounds__(256) void k_pool_z(const float* __restrict__ tok,
                                                const float* __restrict__ pos,
                                                float* __restrict__ z) {
    int gid = blockIdx.x * 256 + threadIdx.x;
    int c = gid & 255;
    int n = (gid >> 8) % SEQL;
    int b = gid / (256 * SEQL);
    int oh = n / 56, ow = n % 56;
    const float* tp = tok + ((long)b * 112 * 112) * 256 + c;
    float m = -1e30f;
#pragma unroll
    for (int kh = 0; kh < 3; kh++) {
        int h = oh * 2 - 1 + kh;
        if ((unsigned)h >= 112u) continue;
#pragma unroll
        for (int kw = 0; kw < 3; kw++) {
            int w = ow * 2 - 1 + kw;
            if ((unsigned)w < 112u) m = fmaxf(m, tp[(long)(h * 112 + w) * 256]);
        }
    }
    z[gid] = m + pos[n * 256 + c];
}

// ---------------- GEMM with fused layernorm on A (A = LN(Z) rows) ----------------
// When dovt!=0 (qkv projection), the Q columns (col<256) are pre-scaled by 0.125
// (exact power-of-2) so k_flash skips the softmax input scaling.
__global__ __launch_bounds__(256) void k_gemm_ln(const float* __restrict__ Z,
                                                 const uint16_t* __restrict__ W,
                                                 const float* __restrict__ lns,
                                                 const float* __restrict__ lnb,
                                                 const float* __restrict__ bias,
                                                 uint16_t* __restrict__ C,
                                                 uint16_t* __restrict__ VT,
                                                 int N, int dogelu, int dovt) {
    __shared__ uint16_t As[128 * 40], Bs[128 * 40];
    __shared__ float mu[128], rsd[128];
    int tid = threadIdx.x;
    int lane = tid & 63, wave = tid >> 6;
    int wm = wave >> 1, wn = wave & 1;
    int m0 = blockIdx.y * 128, n0 = blockIdx.x * 128;
    {
        int row = tid >> 1, hf = tid & 1;
        const float* zr = Z + (long)(m0 + row) * 256 + hf * 128;
        float s = 0.f, sq = 0.f;
        for (int i = 0; i < 128; i++) { float v = zr[i]; s += v; sq += v * v; }
        s += __shfl_xor(s, 1); sq += __shfl_xor(sq, 1);
        if (hf == 0) {
            float m = s * (1.0f / 256.0f);
            mu[row] = m;
            rsd[row] = rsqrtf(sq * (1.0f / 256.0f) - m * m + 1e-5f);
        }
    }
    f32x4 acc[4][4];
#pragma unroll
    for (int i = 0; i < 4; i++)
#pragma unroll
        for (int j = 0; j < 4; j++) acc[i][j] = (f32x4){0.f, 0.f, 0.f, 0.f};
    int rl = lane & 15, kq = (lane >> 4) * 8;
    for (int k0 = 0; k0 < 256; k0 += 32) {
        __syncthreads();
#pragma unroll
        for (int c2 = 0; c2 < 16; c2++) {
            int idx = c2 * 256 + tid;
            int col = idx & 31, row = idx >> 5;
            float v = Z[(long)(m0 + row) * 256 + k0 + col];
            v = (v - mu[row]) * rsd[row] * lns[k0 + col] + lnb[k0 + col];
            As[row * 40 + col] = bf16u(v);
        }
#pragma unroll
        for (int c = 0; c < 2; c++) {
            int idx = c * 256 + tid;
            int row = idx >> 2, k8 = (idx & 3) * 8;
            *(uint4*)&Bs[row * 40 + k8] = *(const uint4*)&W[(long)(n0 + row) * 256 + k0 + k8];
        }
        __syncthreads();
        v8s a[4], bb[4];
#pragma unroll
        for (int i = 0; i < 4; i++) a[i] = *(const v8s*)&As[(wm * 64 + i * 16 + rl) * 40 + kq];
#pragma unroll
        for (int j = 0; j < 4; j++) bb[j] = *(const v8s*)&Bs[(wn * 64 + j * 16 + rl) * 40 + kq];
#pragma unroll
        for (int i = 0; i < 4; i++)
#pragma unroll
            for (int j = 0; j < 4; j++)
                acc[i][j] = __builtin_amdgcn_mfma_f32_16x16x32_bf16(a[i], bb[j], acc[i][j], 0, 0, 0);
    }
    int rq = (lane >> 4) * 4;
    bool vt = (dovt != 0) && (n0 >= 512);
#pragma unroll
    for (int i = 0; i < 4; i++) {
#pragma unroll
        for (int j = 0; j < 4; j++) {
            int col = n0 + wn * 64 + j * 16 + rl;
            float bval = bias[col];
#pragma unroll
            for (int r = 0; r < 4; r++) {
                int row = m0 + wm * 64 + i * 16 + rq + r;
                float v = acc[i][j][r] + bval;
                if (dogelu) v = 0.5f * v * (1.0f + erff(v * 0.70710678118654752f));
                if (dovt != 0 && col < 256) v *= 0.125f;   // pre-scale Q (exact)
                if (vt) {
                    int hv = col - 512;
                    int h = hv >> 6, d = hv & 63;
                    int bb2 = row / SEQL, nn = row - bb2 * SEQL;
                    VT[((long)(bb2 * 4 + h) * 64 + d) * SEQL + nn] = bf16u(v);
                } else {
                    C[(long)row * N + col] = bf16u(v);
                }
            }
        }
    }
}

// ---------------- plain bf16 GEMM (A bf16), resid fp32 += ----------------
__global__ __launch_bounds__(256) void k_gemm(const uint16_t* __restrict__ A,
                                              const uint16_t* __restrict__ W,
                                              const float* __restrict__ bias,
                                              float* __restrict__ C,
                                              int M, int N, int K) {
    __shared__ uint16_t As[128 * 40], Bs[128 * 40];
    int tid = threadIdx.x;
    int lane = tid & 63, wave = tid >> 6;
    int wm = wave >> 1, wn = wave & 1;
    int m0 = blockIdx.y * 128, n0 = blockIdx.x * 128;
    f32x4 acc[4][4];
#pragma unroll
    for (int i = 0; i < 4; i++)
#pragma unroll
        for (int j = 0; j < 4; j++) acc[i][j] = (f32x4){0.f, 0.f, 0.f, 0.f};
    int rl = lane & 15, kq = (lane >> 4) * 8;
    for (int k0 = 0; k0 < K; k0 += 32) {
        __syncthreads();
#pragma unroll
        for (int c = 0; c < 2; c++) {
            int idx = c * 256 + tid;
            int row = idx >> 2, k8 = (idx & 3) * 8;
            *(uint4*)&As[row * 40 + k8] = *(const uint4*)&A[(long)(m0 + row) * K + k0 + k8];
            *(uint4*)&Bs[row * 40 + k8] = *(const uint4*)&W[(long)(n0 + row) * K + k0 + k8];
        }
        __syncthreads();
        v8s a[4], bb[4];
#pragma unroll
        for (int i = 0; i < 4; i++) a[i] = *(const v8s*)&As[(wm * 64 + i * 16 + rl) * 40 + kq];
#pragma unroll
        for (int j = 0; j < 4; j++) bb[j] = *(const v8s*)&Bs[(wn * 64 + j * 16 + rl) * 40 + kq];
#pragma unroll
        for (int i = 0; i < 4; i++)
#pragma unroll
            for (int j = 0; j < 4; j++)
                acc[i][j] = __builtin_amdgcn_mfma_f32_16x16x32_bf16(a[i], bb[j], acc[i][j], 0, 0, 0);
    }
    int rq = (lane >> 4) * 4;
#pragma unroll
    for (int i = 0; i < 4; i++) {
#pragma unroll
        for (int j = 0; j < 4; j++) {
            int col = n0 + wn * 64 + j * 16 + rl;
            float bval = bias[col];
#pragma unroll
            for (int r = 0; r < 4; r++) {
                int row = m0 + wm * 64 + i * 16 + rq + r;
                C[(long)row * N + col] += acc[i][j][r] + bval;
            }
        }
    }
}

// ---------------- flash attention, bf16 MFMA, double-buffered K/V staging ----------
// Q pre-scaled by 0.125 in k_gemm_ln. K/V tile kt+1 loads issue at the top of tile
// kt's compute (latency hidden); 1 barrier/kt (was 2). Ps aliases the dead Qs buffer
// (both 9216 B; prologue barrier orders aq reads before first Ps write) -> LDS 46,080
// -> 3 blocks/CU.
__global__ __launch_bounds__(256) void k_flash(const uint16_t* __restrict__ G,
                                               const uint16_t* __restrict__ VT,
                                               uint16_t* __restrict__ o) {
    __shared__ __align__(16) uint32_t QP[64 * 36];                // Qs, then Ps alias
    __shared__ __align__(16) uint32_t Ks[2][64 * 36], Vt[2][64 * 36];
    int tid = threadIdx.x;
    int lane = tid & 63, wv = tid >> 6;
    int qt = blockIdx.x, h = blockIdx.y, b = blockIdx.z;
    long base = (long)b * SEQL * 768 + h * 64;
    long vtbase = ((long)(b * 4 + h) * 64) * SEQL;
#pragma unroll
    for (int it = 0; it < 2; it++) {
        int idx = it * 256 + tid;
        int q8 = idx & 7, r = idx >> 3;
        *(uint4*)&QP[r * 36 + q8 * 4] = *(const uint4*)&G[base + (long)(qt * 64 + r) * 768 + q8 * 8];
    }
    // stage K/V tile 0 into buf 0
#pragma unroll
    for (int it = 0; it < 2; it++) {
        int idx = it * 256 + tid;
        int q8 = idx & 7, r = idx >> 3;
        *(uint4*)&Ks[0][r * 36 + q8 * 4] =
            *(const uint4*)&G[base + (long)r * 768 + 256 + q8 * 8];
    }
#pragma unroll
    for (int it = 0; it < 2; it++) {
        int idx = it * 256 + tid;
        int r8 = idx & 7, d = idx >> 3;
        *(uint4*)&Vt[0][d * 36 + r8 * 4] =
            *(const uint4*)&VT[vtbase + (long)d * SEQL + r8 * 8];
    }
    int g = lane >> 4, tl = lane & 15;
    int qr0 = wv * 16;
    __syncthreads();
    v8s aq[2];
#pragma unroll
    for (int ks = 0; ks < 2; ks++)
        aq[ks] = *(const v8s*)&QP[(qr0 + tl) * 36 + ks * 16 + g * 4];
    __syncthreads();   // all aq reads done before Ps (alias of QP) is written
    uint16_t* Ps = (uint16_t*)QP;   // [64][72] u16 = 9216 B

    float m_[4], l_[4];
    f32x4 ov[4];
#pragma unroll
    for (int r = 0; r < 4; r++) { m_[r] = -1e30f; l_[r] = 0.f; }
#pragma unroll
    for (int j = 0; j < 4; j++) ov[j] = (f32x4){0.f, 0.f, 0.f, 0.f};

    for (int kt = 0; kt < 49; kt++) {
        int cur = kt & 1;
        if (kt < 48) {
            int nk = kt + 1;
#pragma unroll
            for (int it = 0; it < 2; it++) {
                int idx = it * 256 + tid;
                int q8 = idx & 7, r = idx >> 3;
                *(uint4*)&Ks[cur ^ 1][r * 36 + q8 * 4] =
                    *(const uint4*)&G[base + (long)(nk * 64 + r) * 768 + 256 + q8 * 8];
            }
#pragma unroll
            for (int it = 0; it < 2; it++) {
                int idx = it * 256 + tid;
                int r8 = idx & 7, d = idx >> 3;
                *(uint4*)&Vt[cur ^ 1][d * 36 + r8 * 4] =
                    *(const uint4*)&VT[vtbase + (long)d * SEQL + nk * 64 + r8 * 8];
            }
        }
        f32x4 s[4];
#pragma unroll
        for (int j = 0; j < 4; j++) s[j] = (f32x4){0.f, 0.f, 0.f, 0.f};
#pragma unroll
        for (int ks = 0; ks < 2; ks++) {
#pragma unroll
            for (int j = 0; j < 4; j++) {
                v8s bk = *(const v8s*)&Ks[cur][(j * 16 + tl) * 36 + ks * 16 + g * 4];
                s[j] = __builtin_amdgcn_mfma_f32_16x16x32_bf16(aq[ks], bk, s[j], 0, 0, 0);
            }
        }
        float alpha[4];
#pragma unroll
        for (int r = 0; r < 4; r++) {
            float s0 = s[0][r], s1 = s[1][r];
            float s2 = s[2][r], s3 = s[3][r];
            float mx = fmaxf(fmaxf(s0, s1), fmaxf(s2, s3));
#pragma unroll
            for (int off = 1; off < 16; off <<= 1) mx = fmaxf(mx, __shfl_xor(mx, off));
            float nm = fmaxf(m_[r], mx);
            alpha[r] = __expf(m_[r] - nm);
            float rs = 0.f;
#pragma unroll
            for (int j = 0; j < 4; j++) {
                float p = __expf(s[j][r] - nm);
                s[j][r] = p; rs += p;
            }
#pragma unroll
            for (int off = 1; off < 16; off <<= 1) rs += __shfl_xor(rs, off);
            l_[r] = l_[r] * alpha[r] + rs;
            m_[r] = nm;
        }
#pragma unroll
        for (int j = 0; j < 4; j++)
#pragma unroll
            for (int r = 0; r < 4; r++) ov[j][r] *= alpha[r];
#pragma unroll
        for (int j = 0; j < 4; j++)
#pragma unroll
            for (int r = 0; r < 4; r++)
                Ps[(qr0 + g * 4 + r) * 72 + j * 16 + tl] = bf16u(s[j][r]);
#pragma unroll
        for (int ks = 0; ks < 2; ks++) {
            v8s ap = *(const v8s*)&Ps[(qr0 + tl) * 72 + ks * 32 + g * 8];
#pragma unroll
            for (int jd = 0; jd < 4; jd++) {
                v8s bv = *(const v8s*)&Vt[cur][(jd * 16 + tl) * 36 + ks * 16 + g * 4];
                ov[jd] = __builtin_amdgcn_mfma_f32_16x16x32_bf16(ap, bv, ov[jd], 0, 0, 0);
            }
        }
        __syncthreads();   // Ks/Vt[cur^1] staged+visible; Ks/Vt[cur] + Ps reads done
    }
    long ob = ((long)b * SEQL + qt * 64) * 256 + h * 64;
#pragma unroll
    for (int r = 0; r < 4; r++) {
        float inv = 1.0f / l_[r];
        int row = qr0 + g * 4 + r;
#pragma unroll
        for (int jd = 0; jd < 4; jd++)
            o[ob + (long)row * 256 + jd * 16 + tl] = bf16u(ov[jd][r] * inv);
    }
}

// ---------------- parallel tail ----------------------------------------------------
// Phase 1: per-row LN stats + pool logit (grid 49 x 4; 196 blocks)
__global__ __launch_bounds__(256) void k_tail_rows(const float* __restrict__ Z,
                                                   const float* __restrict__ g,
                                                   const float* __restrict__ be,
                                                   const float* __restrict__ pw,
                                                   const float* __restrict__ pb,
                                                   float* __restrict__ LG,
                                                   float* __restrict__ MU,
                                                   float* __restrict__ RS) {
    int tid = threadIdx.x;
    int wv = tid >> 6, lane = tid & 63;
    int b = blockIdx.y;
    int r0 = blockIdx.x * 64;
    const float* Zb = Z + (long)b * SEQL * 256;
    for (int r = r0 + wv; r < r0 + 64; r += 4) {
        const float* xr = Zb + (long)r * 256;
        float v0 = xr[lane], v1 = xr[lane + 64], v2 = xr[lane + 128], v3 = xr[lane + 192];
        float s = v0 + v1 + v2 + v3;
#pragma unroll
        for (int off = 1; off < 64; off <<= 1) s += __shfl_xor(s, off);
        float mean = s * (1.0f / 256.0f);
        float d0 = v0 - mean, d1 = v1 - mean, d2 = v2 - mean, d3 = v3 - mean;
        float sq = d0 * d0 + d1 * d1 + d2 * d2 + d3 * d3;
#pragma unroll
        for (int off = 1; off < 64; off <<= 1) sq += __shfl_xor(sq, off);
        float rs_ = rsqrtf(sq * (1.0f / 256.0f) + 1e-5f);
        float a = (d0 * rs_ * g[lane] + be[lane]) * pw[lane]
                + (d1 * rs_ * g[lane + 64] + be[lane + 64]) * pw[lane + 64]
                + (d2 * rs_ * g[lane + 128] + be[lane + 128]) * pw[lane + 128]
                + (d3 * rs_ * g[lane + 192] + be[lane + 192]) * pw[lane + 192];
#pragma unroll
        for (int off = 1; off < 64; off <<= 1) a += __shfl_xor(a, off);
        if (lane == 0) {
            LG[b * SEQL + r] = a + pb[0];
            MU[b * SEQL + r] = mean;
            RS[b * SEQL + r] = rs_;
        }
    }
}

// Phase 2: softmax over tokens; fold p*rs in place; sB = sum p*mu*rs (grid 4)
__global__ __launch_bounds__(256) void k_tail_sm(const float* __restrict__ LG,
                                                 const float* __restrict__ MU,
                                                 float* __restrict__ RSW,
                                                 float* __restrict__ SB) {
    __shared__ float red[256];
    int b = blockIdx.x, tid = threadIdx.x;
    const float* lg = LG + (long)b * SEQL;
    const float* mu = MU + (long)b * SEQL;
    float* rw = RSW + (long)b * SEQL;
    float m = -1e30f;
    for (int i = tid; i < SEQL; i += 256) m = fmaxf(m, lg[i]);
    red[tid] = m; __syncthreads();
    for (int s = 128; s > 0; s >>= 1) {
        if (tid < s) red[tid] = fmaxf(red[tid], red[tid + s]);
        __syncthreads();
    }
    float M = red[0]; __syncthreads();
    float sum = 0.f;
    for (int i = tid; i < SEQL; i += 256) sum += expf(lg[i] - M);
    red[tid] = sum; __syncthreads();
    for (int s = 128; s > 0; s >>= 1) {
        if (tid < s) red[tid] += red[tid + s];
        __syncthreads();
    }
    float inv = 1.0f / red[0];
    __syncthreads();
    float pB = 0.f;
    for (int i = tid; i < SEQL; i += 256) {
        float p = expf(lg[i] - M) * inv;
        float rs_ = rw[i];
        pB += p * mu[i] * rs_;
        rw[i] = p * rs_;
    }
    red[tid] = pB; __syncthreads();
    for (int s = 128; s > 0; s >>= 1) {
        if (tid < s) red[tid] += red[tid + s];
        __syncthreads();
    }
    if (tid == 0) SB[b] = red[0];
}

// Phase 3: partial weighted column-sum acc[d] = sum_n (p*rs)[n] * Z[n][d] (grid 49 x 4)
__global__ __launch_bounds__(256) void k_tail_gemv(const float* __restrict__ Z,
                                                   const float* __restrict__ RSW,
                                                   float* __restrict__ ACCP) {
    __shared__ float wsm[64];
    int b = blockIdx.y, tid = threadIdx.x;
    int n0 = blockIdx.x * 64;
    if (tid < 64) wsm[tid] = RSW[(long)b * SEQL + n0 + tid];
    __syncthreads();
    const float* Zb = Z + ((long)b * SEQL + n0) * 256;
    float acc = 0.f;
#pragma unroll 8
    for (int n = 0; n < 64; n++) acc = fmaf(wsm[n], Zb[(long)n * 256 + tid], acc);
    ACCP[((long)blockIdx.x * 4 + b) * 256 + tid] = acc;
}

// Phase 4: finalize pooled + classifier head (grid 4)
__global__ __launch_bounds__(256) void k_tail_head(const float* __restrict__ ACCP,
                                                   const float* __restrict__ SB,
                                                   const float* __restrict__ g,
                                                   const float* __restrict__ be,
                                                   const float* __restrict__ hw,
                                                   const float* __restrict__ hb,
                                                   float* __restrict__ out) {
    __shared__ float pooled[256];
    int b = blockIdx.x, tid = threadIdx.x;
    float s = 0.f;
    for (int c = 0; c < 49; c++) s += ACCP[((long)c * 4 + b) * 256 + tid];
    pooled[tid] = g[tid] * (s - SB[b]) + be[tid];
    __syncthreads();
    if (tid < 101) {
        float a = hb[tid];
        for (int d = 0; d < 256; d++) a = fmaf(pooled[d], hw[tid * 256 + d], a);
        out[b * 101 + tid] = a;
    }
}

// ---------------------------------------------------------------------------
extern "C" void kernel_launch(void* const* d_in, const int* in_sizes, int n_in,
                              void* d_out, int out_size, void* d_ws, size_t ws_size,
                              hipStream_t stream) {
    (void)in_sizes; (void)n_in; (void)out_size; (void)ws_size;
    const float* x     = (const float*)d_in[0];
    const float* w1    = (const float*)d_in[1];
    const float* w2    = (const float*)d_in[2];
    const float* w3    = (const float*)d_in[3];
    const float* tokw  = (const float*)d_in[4];
    const float* pos   = (const float*)d_in[5];
    const float* ln1s  = (const float*)d_in[6];
    const float* ln1b  = (const float*)d_in[7];
    const float* qkvw  = (const float*)d_in[8];
    const float* qkvb  = (const float*)d_in[9];
    const float* projw = (const float*)d_in[10];
    const float* projb = (const float*)d_in[11];
    const float* ln2s  = (const float*)d_in[12];
    const float* ln2b  = (const float*)d_in[13];
    const float* fc1w  = (const float*)d_in[14];
    const float* fc1b  = (const float*)d_in[15];
    const float* fc2w  = (const float*)d_in[16];
    const float* fc2b  = (const float*)d_in[17];
    const float* lnfs  = (const float*)d_in[18];
    const float* lnfb  = (const float*)d_in[19];
    const float* poolw = (const float*)d_in[20];
    const float* poolb = (const float*)d_in[21];
    const float* headw = (const float*)d_in[22];
    const float* headb = (const float*)d_in[23];
    float* out = (float*)d_out;
    char* ws = (char*)d_ws;

    uint64_t* B1P = (uint64_t*)(ws + 0);                  // 14,450,688
    uint32_t* B2P = (uint32_t*)(ws + 14450688);           //  2,408,448
    float*    H3  = (float*)(ws + 16859136);              //  2,408,448
    uint16_t* W1B = (uint16_t*)(ws + 19267584);           //     57,344 (legacy layout)
    uint64_t* WP2 = (uint64_t*)(ws + 19324928);           //     37,632 (legacy, unused)
    uint64_t* WN2 = (uint64_t*)(ws + 19362560);           //     37,632 (legacy, unused)
    uint32_t* WP3 = (uint32_t*)(ws + 19400192);           //      2,048
    uint32_t* WN3 = (uint32_t*)(ws + 19402240);           //      2,048
    uint16_t* WQb = (uint16_t*)(ws + 19404288);           //  2,752,512
    uint16_t* WPb = (uint16_t*)(ws + 22156800);           //    917,504
    uint16_t* W1b = (uint16_t*)(ws + 23074304);           //  1,835,008
    uint16_t* W2b = (uint16_t*)(ws + 24909312);           //  1,835,008
    // X3 (104,633,856 B) aliases TOK..VT region — dead until after conv1m
    uint16_t* X3  = (uint16_t*)(ws + 26744320);
    float*    TOK = (float*)(ws + 26744320);              // 51,380,224 [b][h][w][c]
    float*    Z   = (float*)(ws + 78124544);              // 12,845,056
    uint16_t* Gbf = (uint16_t*)(ws + 90969600);           // 19,267,584
    uint16_t* Obf = (uint16_t*)(ws + 110237184);          //  6,422,528
    uint16_t* MLPb= (uint16_t*)(ws + 116659712);          // 12,845,056
    uint16_t* VT  = (uint16_t*)(ws + 129504768);          //  6,422,528
    // W2I/W1F: after X3's end (131,378,176), inside VT tail — VT only written by the
    // transformer layers, long after conv1/conv2 have consumed these.
    uint8_t*  W2I = (uint8_t*)(ws + 131378176);           //    301,056
    uint16_t* W1F = (uint16_t*)(ws + 131679232);          //     57,344
    // Tail scratch lives in the (dead-by-then) TOK region:
    float* LG   = (float*)(ws + 26744320);                //     50,176
    float* MU   = (float*)(ws + 26794496);                //     50,176
    float* RSW  = (float*)(ws + 26844672);                //     50,176
    float* SB   = (float*)(ws + 26894848);                //         64
    float* ACCP = (float*)(ws + 26894912);                //    200,704

    k_prep<<<14875, 256, 0, stream>>>(qkvw, projw, fc1w, fc2w, w1, w2, w3,
                                      WQb, WPb, W1b, W2b, W1B, WP2, WN2, WP3, WN3,
                                      (uint32_t*)W2I, W1F);
    k_prepx<<<102182, 256, 0, stream>>>(x, (uint32_t*)X3);

    k_conv1m<<<dim3(224, 9, 4), 256, 0, stream>>>(X3, W1F, B1P);
    k_conv2m<<<dim3(224, 3, 4), 256, 0, stream>>>(B1P, W2I, B2P);
    k_conv3<<<2352, 256, 0, stream>>>(B2P, WP3, WN3, H3);
    k_tok<<<dim3(112, 4), 256, 0, stream>>>(H3, tokw, TOK);
    k_pool_z<<<12544, 256, 0, stream>>>(TOK, pos, Z);

    for (int l = 0; l < 7; l++) {
        k_gemm_ln<<<dim3(6, 98), 256, 0, stream>>>(Z, WQb + (long)l * 196608,
                                                   ln1s + l * 256, ln1b + l * 256,
                                                   qkvb + l * 768, Gbf, VT,
                                                   768, 0, 1);
        k_flash<<<dim3(49, 4, 4), 256, 0, stream>>>(Gbf, VT, Obf);
        k_gemm<<<dim3(2, 98), 256, 0, stream>>>(Obf, WPb + (long)l * 65536,
                                                projb + l * 256, Z,
                                                12544, 256, 256);
        k_gemm_ln<<<dim3(4, 98), 256, 0, stream>>>(Z, W1b + (long)l * 131072,
                                                   ln2s + l * 256, ln2b + l * 256,
                                                   fc1b + l * 512, MLPb, nullptr,
                                                   512, 1, 0);
        k_gemm<<<dim3(2, 98), 256, 0, stream>>>(MLPb, W2b + (long)l * 131072,
                                                fc2b + l * 256, Z,
                                                12544, 256, 512);
    }

    k_tail_rows<<<dim3(49, 4), 256, 0, stream>>>(Z, lnfs, lnfb, poolw, poolb,
                                                 LG, MU, RSW);
    k_tail_sm<<<4, 256, 0, stream>>>(LG, MU, RSW, SB);
    k_tail_gemv<<<dim3(49, 4), 256, 0, stream>>>(Z, RSW, ACCP);
    k_tail_head<<<4, 256, 0, stream>>>(ACCP, SB, lnfs, lnfb, headw, headb, out);
}

// Round 11
// 3085.014 us; speedup vs baseline: 1.0622x; 1.0622x over previous
//
#include <hip/hip_runtime.h>
#include <hip/hip_bf16.h>
#include <cstdint>

#define SEQL 3136

typedef __attribute__((ext_vector_type(8))) short v8s;
typedef __attribute__((ext_vector_type(4))) float f32x4;
typedef __attribute__((ext_vector_type(4))) int v4i;

__device__ __forceinline__ uint16_t bf16u(float f) {
    uint32_t u = __float_as_uint(f);
    uint32_t r = u + 0x7fff + ((u >> 16) & 1);   // RNE
    return (uint16_t)(r >> 16);
}
__device__ __forceinline__ float bf2f(uint16_t b) {
    uint32_t u = ((uint32_t)b) << 16;
    return __uint_as_float(u);
}

// ---------------- merged prep: bf16 weight cvt + conv sign-weight fragment buffers ---
__global__ __launch_bounds__(256) void k_prep(const float* __restrict__ qw,
                                              const float* __restrict__ pw,
                                              const float* __restrict__ f1,
                                              const float* __restrict__ f2,
                                              const float* __restrict__ w1,
                                              const float* __restrict__ w2,
                                              const float* __restrict__ w3,
                                              uint16_t* __restrict__ dq,
                                              uint16_t* __restrict__ dp,
                                              uint16_t* __restrict__ d1,
                                              uint16_t* __restrict__ d2,
                                              uint16_t* __restrict__ w1b,
                                              uint64_t* __restrict__ wp2,
                                              uint64_t* __restrict__ wn2,
                                              uint32_t* __restrict__ wp3,
                                              uint32_t* __restrict__ wn3,
                                              uint32_t* __restrict__ w2i,
                                              uint16_t* __restrict__ w1f) {
    int gid = blockIdx.x * 256 + threadIdx.x;
    if (gid < 1376256) { dq[gid] = bf16u(qw[gid]); return; }
    if (gid < 1835008) { int i = gid - 1376256; dp[i] = bf16u(pw[i]); return; }
    if (gid < 2752512) { int i = gid - 1835008; d1[i] = bf16u(f1[i]); return; }
    if (gid < 3670016) { int i = gid - 2752512; d2[i] = bf16u(f2[i]); return; }
    if (gid < 3698688) {
        // conv1 sign weights as bf16: W1B[kw][oc][c=(ic*3+kd)*7+kh], c=63 -> 0 (legacy)
        int i = gid - 3670016;
        int c = i & 63, oc = (i >> 6) & 63, kw = i >> 12;
        uint16_t v = 0;
        if (c < 63) {
            int ic = c / 21, rem = c % 21, kd = rem / 7, kh = rem % 7;
            float w = w1[((((oc * 3 + ic) * 3 + kd) * 7 + kh) * 7) + kw];
            v = (w > 0.f) ? 0x3F80 : ((w < 0.f) ? 0xBF80 : 0);
        }
        w1b[i] = v;
        return;
    }
    if (gid < 3703392) {
        int i = gid - 3698688;
        int oc = i / 147, r = i % 147;
        uint64_t p = 0, n = 0;
        for (int ic = 0; ic < 64; ic++) {
            float v = w2[(long)oc * 9408 + (long)ic * 147 + r];
            if (v > 0.f) p |= (1ull << ic);
            else if (v < 0.f) n |= (1ull << ic);
        }
        wp2[i] = p; wn2[i] = n;
        return;
    }
    if (gid < 3703833) {
        int i = gid - 3703392;
        int oc = i / 147, r = i % 147;
        uint32_t p = 0, n = 0;
        for (int ic = 0; ic < 32; ic++) {
            float v = w3[(long)oc * 4704 + (long)ic * 147 + r];
            if (v > 0.f) p |= (1u << ic);
            else if (v < 0.f) n |= (1u << ic);
        }
        wp3[i] = p; wn3[i] = n;
        return;
    }
    if (gid < 3779097) {
        // conv2 i8 MFMA B-fragment weights: 75,264 dwords = 301,056 bytes
        int j = gid - 3703833;             // dword index
        int s4 = (j & 3) * 4;              // byte offset within the 16B lane block
        int lane = (j >> 2) & 63;
        int nt = (j >> 8) & 1;
        int r = j >> 9;                    // 0..146 = kd*49 + kh*7 + kw
        int g = lane >> 4, tl = lane & 15;
        int oc = nt * 16 + tl;
        uint32_t out = 0;
        for (int bb = 0; bb < 4; bb++) {
            int ic = g * 16 + s4 + bb;
            float w = w2[(long)oc * 9408 + (long)ic * 147 + r];
            uint32_t s8 = (w > 0.f) ? 0x01u : ((w < 0.f) ? 0xFFu : 0x00u);
            out |= s8 << (8 * bb);
        }
        w2i[j] = out;
        return;
    }
    if (gid < 3807769) {
        // conv1 bf16 MFMA B-fragments, lane-major: 28,672 u16 = 57,344 bytes
        int i = gid - 3779097;
        int e = i & 7;
        int lane = (i >> 3) & 63;
        int f = (i >> 9) & 1;
        int wn = (i >> 10) & 1;
        int ks = (i >> 11) & 1;
        int kw = i >> 12;                  // 0..6
        int tl = lane & 15, g = lane >> 4;
        int oc = wn * 32 + f * 16 + tl;
        int c = ks * 32 + g * 8 + e;
        uint16_t v = 0;
        if (c < 63) {
            int ic = c / 21, rem = c % 21, kd = rem / 7, kh = rem % 7;
            float w = w1[((((oc * 3 + ic) * 3 + kd) * 7 + kh) * 7) + kw];
            v = (w > 0.f) ? 0x3F80 : ((w < 0.f) ? 0xBF80 : 0);
        }
        w1f[i] = v;
    }
}

// ---------------- prepx: 3-way bf16 split of x into padded planes -------------------
// X3[s][b][ic][dslot 27][ih' 232][iw' 232] u16; dslot = d+1 (slot0 = zero plane);
// ih' = ih+3, iw' = iw+3; borders zero. Written as u32 (iw'-pairs).
__global__ __launch_bounds__(256) void k_prepx(const float* __restrict__ x,
                                               uint32_t* __restrict__ X3) {
    int gid = blockIdx.x * 256 + threadIdx.x;
    if (gid >= 26158464) return;
    int iwp = gid % 116;
    int t = gid / 116;
    int ihp = t % 232; t /= 232;
    int dslot = t % 27; t /= 27;
    int ic = t % 3; t /= 3;
    int b = t & 3; int s = t >> 2;
    int d = dslot - 1;
    int ih = ihp - 3;
    uint32_t out = 0;
    if (d >= 0 && (unsigned)ih < 224u) {
        const float* xp = x + ((long)(b * 3 + ic) * 27 + d) * 50176 + ih * 224;
#pragma unroll
        for (int half = 0; half < 2; half++) {
            int iw = 2 * iwp + half - 3;
            float v = ((unsigned)iw < 224u) ? xp[iw] : 0.f;
            uint16_t hi = bf16u(v);
            uint16_t o = hi;
            if (s > 0) {
                float r1 = v - bf2f(hi);
                uint16_t lo = bf16u(r1);
                o = (s == 2) ? bf16u(r1 - bf2f(lo)) : lo;
            }
            out |= ((uint32_t)o) << (16 * half);
        }
    }
    X3[gid] = out;
}

// ---------------- conv1: MFMA implicit GEMM from pre-split X3, packed u64 out --------
// Weights: double-buffered LDS staging of W1F (lane-major, conflict-free ds_read_b128),
// prefetch kw+1 before computing kw; 1 barrier per kw. obits16 aliases Wb[1] (dead in
// epilogue) -> 51.6 KB LDS. oh XCD-swizzled for L2 row reuse (FETCH 357->60MB, r9).
// NOTE: register-staged Xt pipeline (r8) spilled to scratch and regressed 2x.
__device__ __forceinline__ v8s ldA76(const uint16_t* Xt, int colb, int c0) {
    union { v8s v; uint2 u[2]; } t;
    const uint16_t* p = Xt + colb * 76 + c0;
    t.u[0] = *(const uint2*)p;
    t.u[1] = *(const uint2*)(p + 4);
    return t.v;
}

__global__ __launch_bounds__(256) void k_conv1m(const uint16_t* __restrict__ X3,
                                                const uint16_t* __restrict__ w1f,
                                                uint64_t* __restrict__ b1p) {
    __shared__ __align__(16) uint16_t Xt[232 * 76];   // [col][c] stride 76 (38dw, gcd2)
    __shared__ __align__(16) uint16_t Wb[2][4096];    // dbuf weights; Wb[1] = obits alias
    int tid = threadIdx.x;
    int bidx = blockIdx.x;
    int oh = (bidx & 7) * 28 + (bidx >> 3);           // XCD-contiguous oh (224 = 8*28)
    int od = blockIdx.y, b = blockIdx.z;
    int lane = tid & 63, wv = tid >> 6;
    int wm = wv >> 1, wn = wv & 1;
    int tl = lane & 15, g = lane >> 4;

    f32x4 acc[7][2];
#pragma unroll
    for (int mt = 0; mt < 7; mt++) {
        acc[mt][0] = (f32x4){0.f, 0.f, 0.f, 0.f};
        acc[mt][1] = (f32x4){0.f, 0.f, 0.f, 0.f};
    }

    for (int s = 0; s < 3; s++) {
        // Xt/Wb[0] writable: s=0 nothing read yet; s>0 covered by final kw barrier of s-1.
        if (tid < 232) {
            const uint16_t* Xb = X3 + ((long)(s * 4 + b) * 81 + (long)od * 3) * 53824
                               + oh * 232 + tid;
#pragma unroll
            for (int cp = 0; cp < 32; cp++) {
                const int c0 = 2 * cp, c1 = c0 + 1;
                uint32_t v0 = 0, v1 = 0;
                if (c0 < 63) {
                    const int ickd = c0 / 7, kh = c0 % 7;
                    const int ic = ickd / 3, kd = ickd % 3;
                    v0 = Xb[(long)(ic * 27 + kd) * 53824 + kh * 232];
                }
                if (c1 < 63) {
                    const int ickd = c1 / 7, kh = c1 % 7;
                    const int ic = ickd / 3, kd = ickd % 3;
                    v1 = Xb[(long)(ic * 27 + kd) * 53824 + kh * 232];
                }
                *(uint32_t*)&Xt[tid * 76 + c0] = v0 | (v1 << 16);
            }
        }
        {   // stage kw=0 weights into Wb[0] (8 KB, coalesced uint4)
            const uint4* src = (const uint4*)w1f;
            uint4* dst = (uint4*)Wb[0];
            dst[tid] = src[tid];
            dst[256 + tid] = src[256 + tid];
        }
        __syncthreads();   // Xt + Wb[0] visible
        for (int kw = 0; kw < 7; kw++) {
            int cur = kw & 1;
            if (kw < 6) {
                // prefetch kw+1 into the other buffer; latency hides under MFMAs
                const uint4* src = (const uint4*)(w1f + (kw + 1) * 4096);
                uint4* dst = (uint4*)Wb[cur ^ 1];
                dst[tid] = src[tid];
                dst[256 + tid] = src[256 + tid];
            }
#pragma unroll
            for (int ks = 0; ks < 2; ks++) {
                // lane-major: ds_read_b128 at lane*16, conflict-free
                const uint16_t* wfb = &Wb[cur][((ks * 2 + wn) * 2) * 512 + lane * 8];
                v8s b0 = *(const v8s*)wfb;
                v8s b1 = *(const v8s*)(wfb + 512);
#pragma unroll
                for (int mt = 0; mt < 7; mt++) {
                    int colb = (wm * 7 + mt) * 16 + tl + kw;   // Xt index = xcol+3
                    v8s a = ldA76(Xt, colb, ks * 32 + g * 8);
                    acc[mt][0] = __builtin_amdgcn_mfma_f32_16x16x32_bf16(a, b0, acc[mt][0], 0, 0, 0);
                    acc[mt][1] = __builtin_amdgcn_mfma_f32_16x16x32_bf16(a, b1, acc[mt][1], 0, 0, 0);
                }
            }
            __syncthreads();   // Wb[cur^1] written+visible; Wb[cur] reads done
        }
    }
    // epilogue: ballot -> 16-bit oc pieces (obits aliases Wb[1]; all Wb reads done)
    uint16_t* obits16 = (uint16_t*)Wb[1];
#pragma unroll
    for (int mt = 0; mt < 7; mt++)
#pragma unroll
        for (int nt = 0; nt < 2; nt++)
#pragma unroll
            for (int r = 0; r < 4; r++) {
                unsigned long long mask = __ballot(acc[mt][nt][r] > 0.f);
                if (tl == 0) {
                    int ow = (wm * 7 + mt) * 16 + g * 4 + r;
                    obits16[ow * 4 + wn * 2 + nt] = (uint16_t)(mask >> (g * 16));
                }
            }
    __syncthreads();
    if (tid < 224) {
        uint64_t w = (uint64_t)obits16[tid * 4]
                   | ((uint64_t)obits16[tid * 4 + 1] << 16)
                   | ((uint64_t)obits16[tid * 4 + 2] << 32)
                   | ((uint64_t)obits16[tid * 4 + 3] << 48);
        b1p[(((long)b * 9 + od) * 224 + oh) * 224 + tid] = w;
    }
}

// ---------------- conv2: i8 MFMA implicit GEMM over packed bitplanes -----------------
__global__ __launch_bounds__(256) void k_conv2m(const uint64_t* __restrict__ bp1,
                                                const uint8_t* __restrict__ w2i,
                                                uint32_t* __restrict__ b2p) {
    __shared__ __align__(16) uint64_t xs[21 * 232];       // 38,976 B  packed input rows
    __shared__ uint16_t obits16[224 * 2];
    int tid = threadIdx.x;
    int bidx = blockIdx.x;
    int oh = (bidx & 7) * 28 + (bidx >> 3);               // XCD-contiguous oh
    int od = blockIdx.y, b = blockIdx.z;
    int lane = tid & 63, wv = tid >> 6;
    int tl = lane & 15, g = lane >> 4;
    int g2 = g >> 1, sh = (g & 1) * 16;

    // stage all 21 (kd,kh) rows of packed u64 bits, zero-padded borders
    for (int i = tid; i < 21 * 232; i += 256) {
        int row = i / 232, wp = i - row * 232;
        int kd = row / 7, kh = row - kd * 7;
        int d = od * 3 - 1 + kd;
        int h = oh - 3 + kh;
        int w = wp - 3;
        uint64_t v = 0;
        if ((unsigned)d < 9u && (unsigned)h < 224u && (unsigned)w < 224u)
            v = bp1[(((long)b * 9 + d) * 224 + h) * 224 + w];
        xs[i] = v;
    }

    int nmt = (wv < 2) ? 4 : 3;   // waves 0,1: 4 M-tiles; waves 2,3: 3 M-tiles
    v4i acc[4][2];
#pragma unroll
    for (int mi = 0; mi < 4; mi++) {
        acc[mi][0] = (v4i){0, 0, 0, 0};
        acc[mi][1] = (v4i){0, 0, 0, 0};
    }
    __syncthreads();   // xs visible

    for (int row = 0; row < 21; row++) {
        const uint8_t* wr = w2i + (long)row * 14336;      // L2-resident fragments
        const uint32_t* x32 = (const uint32_t*)&xs[row * 232];
#pragma unroll
        for (int kw = 0; kw < 7; kw++) {
            v4i bf0 = *(const v4i*)&wr[(kw * 2 + 0) * 1024 + lane * 16];
            v4i bf1 = *(const v4i*)&wr[(kw * 2 + 1) * 1024 + lane * 16];
#pragma unroll
            for (int mi = 0; mi < 4; mi++) {
                if (mi < nmt) {
                    int mt = wv + mi * 4;
                    // 16 ic bits for this lane's k-chunk (g*16..+15) at position ow+kw
                    uint32_t c = x32[(mt * 16 + tl + kw) * 2 + g2] >> sh;
                    v4i a;
#pragma unroll
                    for (int j = 0; j < 4; j++) {
                        uint32_t d4 = (c >> (4 * j)) & 0xFu;
                        a[j] = (int)((d4 * 0x204081u) & 0x01010101u);
                    }
                    acc[mi][0] = __builtin_amdgcn_mfma_i32_16x16x64_i8(a, bf0, acc[mi][0], 0, 0, 0);
                    acc[mi][1] = __builtin_amdgcn_mfma_i32_16x16x64_i8(a, bf1, acc[mi][1], 0, 0, 0);
                }
            }
        }
    }
    // epilogue: sign bits via ballot, pack 32 oc bits per ow
#pragma unroll
    for (int mi = 0; mi < 4; mi++) {
        if (mi < nmt) {
            int mt = wv + mi * 4;
#pragma unroll
            for (int nt = 0; nt < 2; nt++)
#pragma unroll
                for (int r = 0; r < 4; r++) {
                    unsigned long long mask = __ballot(acc[mi][nt][r] > 0);
                    if (tl == 0)
                        obits16[(mt * 16 + g * 4 + r) * 2 + nt] = (uint16_t)(mask >> (g * 16));
                }
        }
    }
    __syncthreads();
    if (tid < 224) {
        uint32_t wo = (uint32_t)obits16[tid * 2] | ((uint32_t)obits16[tid * 2 + 1] << 16);
        b2p[(((long)b * 3 + od) * 224 + oh) * 224 + tid] = wo;
    }
}

// conv3 via popcount -> fp32 relu count
__global__ __launch_bounds__(256) void k_conv3(const uint32_t* __restrict__ bp2,
                                               const uint32_t* __restrict__ wp,
                                               const uint32_t* __restrict__ wn,
                                               float* __restrict__ h3) {
    int gid = blockIdx.x * 256 + threadIdx.x;  // 602,112
    int q = gid;
    int ow = q % 224; q /= 224;
    int oh = q % 224; q /= 224;
    int oc = q % 3;   int b = q / 3;
    int acc = 0;
    for (int kd = 0; kd < 3; kd++) {
        int d = kd - 1;
        if ((unsigned)d >= 3u) continue;
        for (int kh = 0; kh < 7; kh++) {
            int h = oh - 3 + kh;
            if ((unsigned)h >= 224u) continue;
            const uint32_t* bp = bp2 + ((long)(b * 3 + d) * 224 + h) * 224;
            const uint32_t* mp = wp + ((oc * 3 + kd) * 7 + kh) * 7;
            const uint32_t* mn = wn + ((oc * 3 + kd) * 7 + kh) * 7;
#pragma unroll
            for (int kw = 0; kw < 7; kw++) {
                int w = ow - 3 + kw;
                if ((unsigned)w < 224u) {
                    uint32_t bits = bp[w];
                    acc += __popc(bits & mp[kw]) - __popc(bits & mn[kw]);
                }
            }
        }
    }
    h3[gid] = fmaxf((float)acc, 0.f);
}

// ---------------- tokenizer conv; tok layout [b][h][w][c] ----------------
__global__ __launch_bounds__(256) void k_tok(const float* __restrict__ h3,
                                             const float* __restrict__ wt,
                                             float* __restrict__ tok) {
    __shared__ float xs[3 * 7 * 232];
    int tid = threadIdx.x;
    int oh = blockIdx.x, b = blockIdx.y;
    for (int i = tid; i < 3 * 7 * 232; i += 256) {
        int col = i % 232; int t = i / 232;
        int kh = t % 7; int ic = t / 7;
        int ih = oh * 2 - 3 + kh;
        int iw = col - 3;
        float v = 0.f;
        if ((unsigned)ih < 224u && (unsigned)iw < 224u)
            v = h3[((long)(b * 3 + ic) * 50176) + ih * 224 + iw];
        xs[i] = v;
    }
    __syncthreads();
    int oc = tid;
    float* obase = tok + ((long)(b * 112 + oh) * 112) * 256 + oc;
    for (int chunk = 0; chunk < 4; chunk++) {
        int ow0 = chunk * 28;
        float acc[28];
#pragma unroll
        for (int o2 = 0; o2 < 28; o2++) acc[o2] = 0.f;
        for (int ic = 0; ic < 3; ic++) {
#pragma unroll
            for (int kh = 0; kh < 7; kh++) {
                const float* row = &xs[(ic * 7 + kh) * 232 + ow0 * 2];
                float xv[61];
#pragma unroll
                for (int t = 0; t < 61; t++) xv[t] = row[t];
                const float* wr = wt + (oc * 3 + ic) * 49 + kh * 7;
                float w[7];
#pragma unroll
                for (int kw = 0; kw < 7; kw++) w[kw] = wr[kw];
#pragma unroll
                for (int kw = 0; kw < 7; kw++)
#pragma unroll
                    for (int o2 = 0; o2 < 28; o2++)
                        acc[o2] = fmaf(w[kw], xv[2 * o2 + kw], acc[o2]);
            }
        }
#pragma unroll
        for (int o2 = 0; o2 < 28; o2++)
            obase[(long)(ow0 + o2) * 256] = fmaxf(acc[o2], 0.f);
    }
}

// maxpool 3x3 s2 p1 + pos_emb
__global__ __launch_bounds__(256) void k_pool_z(const float* __restrict__ tok,
                                                const float* __restrict__ pos,
                                                float* __restrict__ z) {
    int gid = blockIdx.x * 256 + threadIdx.x;
    int c = gid & 255;
    int n = (gid >> 8) % SEQL;
    int b = gid / (256 * SEQL);
    int oh = n / 56, ow = n % 56;
    const float* tp = tok + ((long)b * 112 * 112) * 256 + c;
    float m = -1e30f;
#pragma unroll
    for (int kh = 0; kh < 3; kh++) {
        int h = oh * 2 - 1 + kh;
        if ((unsigned)h >= 112u) continue;
#pragma unroll
        for (int kw = 0; kw < 3; kw++) {
            int w = ow * 2 - 1 + kw;
            if ((unsigned)w < 112u) m = fmaxf(m, tp[(long)(h * 112 + w) * 256]);
        }
    }
    z[gid] = m + pos[n * 256 + c];
}

// ---------------- GEMM with fused layernorm on A (A = LN(Z) rows) ----------------
// When dovt!=0 (qkv projection), the Q columns (col<256) are pre-scaled by 0.125
// (exact power-of-2) so k_flash skips the softmax input scaling.
__global__ __launch_bounds__(256) void k_gemm_ln(const float* __restrict__ Z,
                                                 const uint16_t* __restrict__ W,
                                                 const float* __restrict__ lns,
                                                 const float* __restrict__ lnb,
                                                 const float* __restrict__ bias,
                                                 uint16_t* __restrict__ C,
                                                 uint16_t* __restrict__ VT,
                                                 int N, int dogelu, int dovt) {
    __shared__ uint16_t As[128 * 40], Bs[128 * 40];
    __shared__ float mu[128], rsd[128];
    int tid = threadIdx.x;
    int lane = tid & 63, wave = tid >> 6;
    int wm = wave >> 1, wn = wave & 1;
    int m0 = blockIdx.y * 128, n0 = blockIdx.x * 128;
    {
        int row = tid >> 1, hf = tid & 1;
        const float* zr = Z + (long)(m0 + row) * 256 + hf * 128;
        float s = 0.f, sq = 0.f;
        for (int i = 0; i < 128; i++) { float v = zr[i]; s += v; sq += v * v; }
        s += __shfl_xor(s, 1); sq += __shfl_xor(sq, 1);
        if (hf == 0) {
            float m = s * (1.0f / 256.0f);
            mu[row] = m;
            rsd[row] = rsqrtf(sq * (1.0f / 256.0f) - m * m + 1e-5f);
        }
    }
    f32x4 acc[4][4];
#pragma unroll
    for (int i = 0; i < 4; i++)
#pragma unroll
        for (int j = 0; j < 4; j++) acc[i][j] = (f32x4){0.f, 0.f, 0.f, 0.f};
    int rl = lane & 15, kq = (lane >> 4) * 8;
    for (int k0 = 0; k0 < 256; k0 += 32) {
        __syncthreads();
#pragma unroll
        for (int c2 = 0; c2 < 16; c2++) {
            int idx = c2 * 256 + tid;
            int col = idx & 31, row = idx >> 5;
            float v = Z[(long)(m0 + row) * 256 + k0 + col];
            v = (v - mu[row]) * rsd[row] * lns[k0 + col] + lnb[k0 + col];
            As[row * 40 + col] = bf16u(v);
        }
#pragma unroll
        for (int c = 0; c < 2; c++) {
            int idx = c * 256 + tid;
            int row = idx >> 2, k8 = (idx & 3) * 8;
            *(uint4*)&Bs[row * 40 + k8] = *(const uint4*)&W[(long)(n0 + row) * 256 + k0 + k8];
        }
        __syncthreads();
        v8s a[4], bb[4];
#pragma unroll
        for (int i = 0; i < 4; i++) a[i] = *(const v8s*)&As[(wm * 64 + i * 16 + rl) * 40 + kq];
#pragma unroll
        for (int j = 0; j < 4; j++) bb[j] = *(const v8s*)&Bs[(wn * 64 + j * 16 + rl) * 40 + kq];
#pragma unroll
        for (int i = 0; i < 4; i++)
#pragma unroll
            for (int j = 0; j < 4; j++)
                acc[i][j] = __builtin_amdgcn_mfma_f32_16x16x32_bf16(a[i], bb[j], acc[i][j], 0, 0, 0);
    }
    int rq = (lane >> 4) * 4;
    bool vt = (dovt != 0) && (n0 >= 512);
#pragma unroll
    for (int i = 0; i < 4; i++) {
#pragma unroll
        for (int j = 0; j < 4; j++) {
            int col = n0 + wn * 64 + j * 16 + rl;
            float bval = bias[col];
#pragma unroll
            for (int r = 0; r < 4; r++) {
                int row = m0 + wm * 64 + i * 16 + rq + r;
                float v = acc[i][j][r] + bval;
                if (dogelu) v = 0.5f * v * (1.0f + erff(v * 0.70710678118654752f));
                if (dovt != 0 && col < 256) v *= 0.125f;   // pre-scale Q (exact)
                if (vt) {
                    int hv = col - 512;
                    int h = hv >> 6, d = hv & 63;
                    int bb2 = row / SEQL, nn = row - bb2 * SEQL;
                    VT[((long)(bb2 * 4 + h) * 64 + d) * SEQL + nn] = bf16u(v);
                } else {
                    C[(long)row * N + col] = bf16u(v);
                }
            }
        }
    }
}

// ---------------- plain bf16 GEMM (A bf16), resid fp32 += ----------------
__global__ __launch_bounds__(256) void k_gemm(const uint16_t* __restrict__ A,
                                              const uint16_t* __restrict__ W,
                                              const float* __restrict__ bias,
                                              float* __restrict__ C,
                                              int M, int N, int K) {
    __shared__ uint16_t As[128 * 40], Bs[128 * 40];
    int tid = threadIdx.x;
    int lane = tid & 63, wave = tid >> 6;
    int wm = wave >> 1, wn = wave & 1;
    int m0 = blockIdx.y * 128, n0 = blockIdx.x * 128;
    f32x4 acc[4][4];
#pragma unroll
    for (int i = 0; i < 4; i++)
#pragma unroll
        for (int j = 0; j < 4; j++) acc[i][j] = (f32x4){0.f, 0.f, 0.f, 0.f};
    int rl = lane & 15, kq = (lane >> 4) * 8;
    for (int k0 = 0; k0 < K; k0 += 32) {
        __syncthreads();
#pragma unroll
        for (int c = 0; c < 2; c++) {
            int idx = c * 256 + tid;
            int row = idx >> 2, k8 = (idx & 3) * 8;
            *(uint4*)&As[row * 40 + k8] = *(const uint4*)&A[(long)(m0 + row) * K + k0 + k8];
            *(uint4*)&Bs[row * 40 + k8] = *(const uint4*)&W[(long)(n0 + row) * K + k0 + k8];
        }
        __syncthreads();
        v8s a[4], bb[4];
#pragma unroll
        for (int i = 0; i < 4; i++) a[i] = *(const v8s*)&As[(wm * 64 + i * 16 + rl) * 40 + kq];
#pragma unroll
        for (int j = 0; j < 4; j++) bb[j] = *(const v8s*)&Bs[(wn * 64 + j * 16 + rl) * 40 + kq];
#pragma unroll
        for (int i = 0; i < 4; i++)
#pragma unroll
            for (int j = 0; j < 4; j++)
                acc[i][j] = __builtin_amdgcn_mfma_f32_16x16x32_bf16(a[i], bb[j], acc[i][j], 0, 0, 0);
    }
    int rq = (lane >> 4) * 4;
#pragma unroll
    for (int i = 0; i < 4; i++) {
#pragma unroll
        for (int j = 0; j < 4; j++) {
            int col = n0 + wn * 64 + j * 16 + rl;
            float bval = bias[col];
#pragma unroll
            for (int r = 0; r < 4; r++) {
                int row = m0 + wm * 64 + i * 16 + rq + r;
                C[(long)row * N + col] += acc[i][j][r] + bval;
            }
        }
    }
}

// ---------------- bf16 GEMM, BM=128 x BN=64 tiles (for N=256: grid (4,98)=392 blocks,
// 2x the blocks of the 128x128 version -> better CU coverage). resid fp32 +=.
__global__ __launch_bounds__(256) void k_gemm64(const uint16_t* __restrict__ A,
                                                const uint16_t* __restrict__ W,
                                                const float* __restrict__ bias,
                                                float* __restrict__ C,
                                                int M, int N, int K) {
    __shared__ uint16_t As[128 * 40], Bs[64 * 40];
    int tid = threadIdx.x;
    int lane = tid & 63, wave = tid >> 6;
    int wm = wave >> 1, wn = wave & 1;
    int m0 = blockIdx.y * 128, n0 = blockIdx.x * 64;
    f32x4 acc[4][2];
#pragma unroll
    for (int i = 0; i < 4; i++)
#pragma unroll
        for (int j = 0; j < 2; j++) acc[i][j] = (f32x4){0.f, 0.f, 0.f, 0.f};
    int rl = lane & 15, kq = (lane >> 4) * 8;
    for (int k0 = 0; k0 < K; k0 += 32) {
        __syncthreads();
#pragma unroll
        for (int c = 0; c < 2; c++) {
            int idx = c * 256 + tid;
            int row = idx >> 2, k8 = (idx & 3) * 8;
            *(uint4*)&As[row * 40 + k8] = *(const uint4*)&A[(long)(m0 + row) * K + k0 + k8];
        }
        {
            int row = tid >> 2, k8 = (tid & 3) * 8;
            *(uint4*)&Bs[row * 40 + k8] = *(const uint4*)&W[(long)(n0 + row) * K + k0 + k8];
        }
        __syncthreads();
        v8s a[4], bb[2];
#pragma unroll
        for (int i = 0; i < 4; i++) a[i] = *(const v8s*)&As[(wm * 64 + i * 16 + rl) * 40 + kq];
#pragma unroll
        for (int j = 0; j < 2; j++) bb[j] = *(const v8s*)&Bs[(wn * 32 + j * 16 + rl) * 40 + kq];
#pragma unroll
        for (int i = 0; i < 4; i++)
#pragma unroll
            for (int j = 0; j < 2; j++)
                acc[i][j] = __builtin_amdgcn_mfma_f32_16x16x32_bf16(a[i], bb[j], acc[i][j], 0, 0, 0);
    }
    int rq = (lane >> 4) * 4;
#pragma unroll
    for (int i = 0; i < 4; i++) {
#pragma unroll
        for (int j = 0; j < 2; j++) {
            int col = n0 + wn * 32 + j * 16 + rl;
            float bval = bias[col];
#pragma unroll
            for (int r = 0; r < 4; r++) {
                int row = m0 + wm * 64 + i * 16 + rq + r;
                C[(long)row * N + col] += acc[i][j][r] + bval;
            }
        }
    }
}

// ---------------- flash attention, bf16 MFMA, pre-transposed V, b128 staging -------
// Q pre-scaled by 0.125 in k_gemm_ln (no per-iteration scaling here).
// r10 NOTE: K/V double-buffering (46KB LDS) dropped occupancy 4->3 blocks/CU and
// regressed +24us/dispatch — keep the 36,864 B single-buffer layout (4 blocks/CU).
__global__ __launch_bounds__(256) void k_flash(const uint16_t* __restrict__ G,
                                               const uint16_t* __restrict__ VT,
                                               uint16_t* __restrict__ o) {
    __shared__ __align__(16) uint32_t Qs[64 * 36], Ks[64 * 36], Vt[64 * 36];
    __shared__ __align__(16) uint16_t Ps[64 * 72];
    int tid = threadIdx.x;
    int lane = tid & 63, wv = tid >> 6;
    int qt = blockIdx.x, h = blockIdx.y, b = blockIdx.z;
    long base = (long)b * SEQL * 768 + h * 64;
    long vtbase = ((long)(b * 4 + h) * 64) * SEQL;
#pragma unroll
    for (int it = 0; it < 2; it++) {
        int idx = it * 256 + tid;
        int q8 = idx & 7, r = idx >> 3;
        *(uint4*)&Qs[r * 36 + q8 * 4] = *(const uint4*)&G[base + (long)(qt * 64 + r) * 768 + q8 * 8];
    }
    int g = lane >> 4, tl = lane & 15;
    int qr0 = wv * 16;
    __syncthreads();
    v8s aq[2];
#pragma unroll
    for (int ks = 0; ks < 2; ks++)
        aq[ks] = *(const v8s*)&Qs[(qr0 + tl) * 36 + ks * 16 + g * 4];

    float m_[4], l_[4];
    f32x4 ov[4];
#pragma unroll
    for (int r = 0; r < 4; r++) { m_[r] = -1e30f; l_[r] = 0.f; }
#pragma unroll
    for (int j = 0; j < 4; j++) ov[j] = (f32x4){0.f, 0.f, 0.f, 0.f};

    for (int kt = 0; kt < 49; kt++) {
        __syncthreads();
#pragma unroll
        for (int it = 0; it < 2; it++) {
            int idx = it * 256 + tid;
            int q8 = idx & 7, r = idx >> 3;
            *(uint4*)&Ks[r * 36 + q8 * 4] =
                *(const uint4*)&G[base + (long)(kt * 64 + r) * 768 + 256 + q8 * 8];
        }
#pragma unroll
        for (int it = 0; it < 2; it++) {
            int idx = it * 256 + tid;
            int r8 = idx & 7, d = idx >> 3;
            *(uint4*)&Vt[d * 36 + r8 * 4] =
                *(const uint4*)&VT[vtbase + (long)d * SEQL + kt * 64 + r8 * 8];
        }
        __syncthreads();
        f32x4 s[4];
#pragma unroll
        for (int j = 0; j < 4; j++) s[j] = (f32x4){0.f, 0.f, 0.f, 0.f};
#pragma unroll
        for (int ks = 0; ks < 2; ks++) {
#pragma unroll
            for (int j = 0; j < 4; j++) {
                v8s bk = *(const v8s*)&Ks[(j * 16 + tl) * 36 + ks * 16 + g * 4];
                s[j] = __builtin_amdgcn_mfma_f32_16x16x32_bf16(aq[ks], bk, s[j], 0, 0, 0);
            }
        }
        float alpha[4];
#pragma unroll
        for (int r = 0; r < 4; r++) {
            float s0 = s[0][r], s1 = s[1][r];
            float s2 = s[2][r], s3 = s[3][r];
            float mx = fmaxf(fmaxf(s0, s1), fmaxf(s2, s3));
#pragma unroll
            for (int off = 1; off < 16; off <<= 1) mx = fmaxf(mx, __shfl_xor(mx, off));
            float nm = fmaxf(m_[r], mx);
            alpha[r] = __expf(m_[r] - nm);
            float rs = 0.f;
#pragma unroll
            for (int j = 0; j < 4; j++) {
                float p = __expf(s[j][r] - nm);
                s[j][r] = p; rs += p;
            }
#pragma unroll
            for (int off = 1; off < 16; off <<= 1) rs += __shfl_xor(rs, off);
            l_[r] = l_[r] * alpha[r] + rs;
            m_[r] = nm;
        }
#pragma unroll
        for (int j = 0; j < 4; j++)
#pragma unroll
            for (int r = 0; r < 4; r++) ov[j][r] *= alpha[r];
#pragma unroll
        for (int j = 0; j < 4; j++)
#pragma unroll
            for (int r = 0; r < 4; r++)
                Ps[(qr0 + g * 4 + r) * 72 + j * 16 + tl] = bf16u(s[j][r]);
#pragma unroll
        for (int ks = 0; ks < 2; ks++) {
            v8s ap = *(const v8s*)&Ps[(qr0 + tl) * 72 + ks * 32 + g * 8];
#pragma unroll
            for (int jd = 0; jd < 4; jd++) {
                v8s bv = *(const v8s*)&Vt[(jd * 16 + tl) * 36 + ks * 16 + g * 4];
                ov[jd] = __builtin_amdgcn_mfma_f32_16x16x32_bf16(ap, bv, ov[jd], 0, 0, 0);
            }
        }
    }
    long ob = ((long)b * SEQL + qt * 64) * 256 + h * 64;
#pragma unroll
    for (int r = 0; r < 4; r++) {
        float inv = 1.0f / l_[r];
        int row = qr0 + g * 4 + r;
#pragma unroll
        for (int jd = 0; jd < 4; jd++)
            o[ob + (long)row * 256 + jd * 16 + tl] = bf16u(ov[jd][r] * inv);
    }
}

// ---------------- parallel tail ----------------------------------------------------
// Phase 1: per-row LN stats + pool logit (grid 49 x 4; 196 blocks)
__global__ __launch_bounds__(256) void k_tail_rows(const float* __restrict__ Z,
                                                   const float* __restrict__ g,
                                                   const float* __restrict__ be,
                                                   const float* __restrict__ pw,
                                                   const float* __restrict__ pb,
                                                   float* __restrict__ LG,
                                                   float* __restrict__ MU,
                                                   float* __restrict__ RS) {
    int tid = threadIdx.x;
    int wv = tid >> 6, lane = tid & 63;
    int b = blockIdx.y;
    int r0 = blockIdx.x * 64;
    const float* Zb = Z + (long)b * SEQL * 256;
    for (int r = r0 + wv; r < r0 + 64; r += 4) {
        const float* xr = Zb + (long)r * 256;
        float v0 = xr[lane], v1 = xr[lane + 64], v2 = xr[lane + 128], v3 = xr[lane + 192];
        float s = v0 + v1 + v2 + v3;
#pragma unroll
        for (int off = 1; off < 64; off <<= 1) s += __shfl_xor(s, off);
        float mean = s * (1.0f / 256.0f);
        float d0 = v0 - mean, d1 = v1 - mean, d2 = v2 - mean, d3 = v3 - mean;
        float sq = d0 * d0 + d1 * d1 + d2 * d2 + d3 * d3;
#pragma unroll
        for (int off = 1; off < 64; off <<= 1) sq += __shfl_xor(sq, off);
        float rs_ = rsqrtf(sq * (1.0f / 256.0f) + 1e-5f);
        float a = (d0 * rs_ * g[lane] + be[lane]) * pw[lane]
                + (d1 * rs_ * g[lane + 64] + be[lane + 64]) * pw[lane + 64]
                + (d2 * rs_ * g[lane + 128] + be[lane + 128]) * pw[lane + 128]
                + (d3 * rs_ * g[lane + 192] + be[lane + 192]) * pw[lane + 192];
#pragma unroll
        for (int off = 1; off < 64; off <<= 1) a += __shfl_xor(a, off);
        if (lane == 0) {
            LG[b * SEQL + r] = a + pb[0];
            MU[b * SEQL + r] = mean;
            RS[b * SEQL + r] = rs_;
        }
    }
}

// Phase 2: softmax over tokens; fold p*rs in place; sB = sum p*mu*rs (grid 4)
__global__ __launch_bounds__(256) void k_tail_sm(const float* __restrict__ LG,
                                                 const float* __restrict__ MU,
                                                 float* __restrict__ RSW,
                                                 float* __restrict__ SB) {
    __shared__ float red[256];
    int b = blockIdx.x, tid = threadIdx.x;
    const float* lg = LG + (long)b * SEQL;
    const float* mu = MU + (long)b * SEQL;
    float* rw = RSW + (long)b * SEQL;
    float m = -1e30f;
    for (int i = tid; i < SEQL; i += 256) m = fmaxf(m, lg[i]);
    red[tid] = m; __syncthreads();
    for (int s = 128; s > 0; s >>= 1) {
        if (tid < s) red[tid] = fmaxf(red[tid], red[tid + s]);
        __syncthreads();
    }
    float M = red[0]; __syncthreads();
    float sum = 0.f;
    for (int i = tid; i < SEQL; i += 256) sum += expf(lg[i] - M);
    red[tid] = sum; __syncthreads();
    for (int s = 128; s > 0; s >>= 1) {
        if (tid < s) red[tid] += red[tid + s];
        __syncthreads();
    }
    float inv = 1.0f / red[0];
    __syncthreads();
    float pB = 0.f;
    for (int i = tid; i < SEQL; i += 256) {
        float p = expf(lg[i] - M) * inv;
        float rs_ = rw[i];
        pB += p * mu[i] * rs_;
        rw[i] = p * rs_;
    }
    red[tid] = pB; __syncthreads();
    for (int s = 128; s > 0; s >>= 1) {
        if (tid < s) red[tid] += red[tid + s];
        __syncthreads();
    }
    if (tid == 0) SB[b] = red[0];
}

// Phase 3: partial weighted column-sum acc[d] = sum_n (p*rs)[n] * Z[n][d] (grid 49 x 4)
__global__ __launch_bounds__(256) void k_tail_gemv(const float* __restrict__ Z,
                                                   const float* __restrict__ RSW,
                                                   float* __restrict__ ACCP) {
    __shared__ float wsm[64];
    int b = blockIdx.y, tid = threadIdx.x;
    int n0 = blockIdx.x * 64;
    if (tid < 64) wsm[tid] = RSW[(long)b * SEQL + n0 + tid];
    __syncthreads();
    const float* Zb = Z + ((long)b * SEQL + n0) * 256;
    float acc = 0.f;
#pragma unroll 8
    for (int n = 0; n < 64; n++) acc = fmaf(wsm[n], Zb[(long)n * 256 + tid], acc);
    ACCP[((long)blockIdx.x * 4 + b) * 256 + tid] = acc;
}

// Phase 4: finalize pooled + classifier head (grid 4)
__global__ __launch_bounds__(256) void k_tail_head(const float* __restrict__ ACCP,
                                                   const float* __restrict__ SB,
                                                   const float* __restrict__ g,
                                                   const float* __restrict__ be,
                                                   const float* __restrict__ hw,
                                                   const float* __restrict__ hb,
                                                   float* __restrict__ out) {
    __shared__ float pooled[256];
    int b = blockIdx.x, tid = threadIdx.x;
    float s = 0.f;
    for (int c = 0; c < 49; c++) s += ACCP[((long)c * 4 + b) * 256 + tid];
    pooled[tid] = g[tid] * (s - SB[b]) + be[tid];
    __syncthreads();
    if (tid < 101) {
        float a = hb[tid];
        for (int d = 0; d < 256; d++) a = fmaf(pooled[d], hw[tid * 256 + d], a);
        out[b * 101 + tid] = a;
    }
}

// ---------------------------------------------------------------------------
extern "C" void kernel_launch(void* const* d_in, const int* in_sizes, int n_in,
                              void* d_out, int out_size, void* d_ws, size_t ws_size,
                              hipStream_t stream) {
    (void)in_sizes; (void)n_in; (void)out_size; (void)ws_size;
    const float* x     = (const float*)d_in[0];
    const float* w1    = (const float*)d_in[1];
    const float* w2    = (const float*)d_in[2];
    const float* w3    = (const float*)d_in[3];
    const float* tokw  = (const float*)d_in[4];
    const float* pos   = (const float*)d_in[5];
    const float* ln1s  = (const float*)d_in[6];
    const float* ln1b  = (const float*)d_in[7];
    const float* qkvw  = (const float*)d_in[8];
    const float* qkvb  = (const float*)d_in[9];
    const float* projw = (const float*)d_in[10];
    const float* projb = (const float*)d_in[11];
    const float* ln2s  = (const float*)d_in[12];
    const float* ln2b  = (const float*)d_in[13];
    const float* fc1w  = (const float*)d_in[14];
    const float* fc1b  = (const float*)d_in[15];
    const float* fc2w  = (const float*)d_in[16];
    const float* fc2b  = (const float*)d_in[17];
    const float* lnfs  = (const float*)d_in[18];
    const float* lnfb  = (const float*)d_in[19];
    const float* poolw = (const float*)d_in[20];
    const float* poolb = (const float*)d_in[21];
    const float* headw = (const float*)d_in[22];
    const float* headb = (const float*)d_in[23];
    float* out = (float*)d_out;
    char* ws = (char*)d_ws;

    uint64_t* B1P = (uint64_t*)(ws + 0);                  // 14,450,688
    uint32_t* B2P = (uint32_t*)(ws + 14450688);           //  2,408,448
    float*    H3  = (float*)(ws + 16859136);              //  2,408,448
    uint16_t* W1B = (uint16_t*)(ws + 19267584);           //     57,344 (legacy layout)
    uint64_t* WP2 = (uint64_t*)(ws + 19324928);           //     37,632 (legacy, unused)
    uint64_t* WN2 = (uint64_t*)(ws + 19362560);           //     37,632 (legacy, unused)
    uint32_t* WP3 = (uint32_t*)(ws + 19400192);           //      2,048
    uint32_t* WN3 = (uint32_t*)(ws + 19402240);           //      2,048
    uint16_t* WQb = (uint16_t*)(ws + 19404288);           //  2,752,512
    uint16_t* WPb = (uint16_t*)(ws + 22156800);           //    917,504
    uint16_t* W1b = (uint16_t*)(ws + 23074304);           //  1,835,008
    uint16_t* W2b = (uint16_t*)(ws + 24909312);           //  1,835,008
    // X3 (104,633,856 B) aliases TOK..VT region — dead until after conv1m
    uint16_t* X3  = (uint16_t*)(ws + 26744320);
    float*    TOK = (float*)(ws + 26744320);              // 51,380,224 [b][h][w][c]
    float*    Z   = (float*)(ws + 78124544);              // 12,845,056
    uint16_t* Gbf = (uint16_t*)(ws + 90969600);           // 19,267,584
    uint16_t* Obf = (uint16_t*)(ws + 110237184);          //  6,422,528
    uint16_t* MLPb= (uint16_t*)(ws + 116659712);          // 12,845,056
    uint16_t* VT  = (uint16_t*)(ws + 129504768);          //  6,422,528
    // W2I/W1F: after X3's end (131,378,176), inside VT tail — VT only written by the
    // transformer layers, long after conv1/conv2 have consumed these.
    uint8_t*  W2I = (uint8_t*)(ws + 131378176);           //    301,056
    uint16_t* W1F = (uint16_t*)(ws + 131679232);          //     57,344
    // Tail scratch lives in the (dead-by-then) TOK region:
    float* LG   = (float*)(ws + 26744320);                //     50,176
    float* MU   = (float*)(ws + 26794496);                //     50,176
    float* RSW  = (float*)(ws + 26844672);                //     50,176
    float* SB   = (float*)(ws + 26894848);                //         64
    float* ACCP = (float*)(ws + 26894912);                //    200,704

    k_prep<<<14875, 256, 0, stream>>>(qkvw, projw, fc1w, fc2w, w1, w2, w3,
                                      WQb, WPb, W1b, W2b, W1B, WP2, WN2, WP3, WN3,
                                      (uint32_t*)W2I, W1F);
    k_prepx<<<102182, 256, 0, stream>>>(x, (uint32_t*)X3);

    k_conv1m<<<dim3(224, 9, 4), 256, 0, stream>>>(X3, W1F, B1P);
    k_conv2m<<<dim3(224, 3, 4), 256, 0, stream>>>(B1P, W2I, B2P);
    k_conv3<<<2352, 256, 0, stream>>>(B2P, WP3, WN3, H3);
    k_tok<<<dim3(112, 4), 256, 0, stream>>>(H3, tokw, TOK);
    k_pool_z<<<12544, 256, 0, stream>>>(TOK, pos, Z);

    for (int l = 0; l < 7; l++) {
        k_gemm_ln<<<dim3(6, 98), 256, 0, stream>>>(Z, WQb + (long)l * 196608,
                                                   ln1s + l * 256, ln1b + l * 256,
                                                   qkvb + l * 768, Gbf, VT,
                                                   768, 0, 1);
        k_flash<<<dim3(49, 4, 4), 256, 0, stream>>>(Gbf, VT, Obf);
        k_gemm64<<<dim3(4, 98), 256, 0, stream>>>(Obf, WPb + (long)l * 65536,
                                                  projb + l * 256, Z,
                                                  12544, 256, 256);
        k_gemm_ln<<<dim3(4, 98), 256, 0, stream>>>(Z, W1b + (long)l * 131072,
                                                   ln2s + l * 256, ln2b + l * 256,
                                                   fc1b + l * 512, MLPb, nullptr,
                                                   512, 1, 0);
        k_gemm64<<<dim3(4, 98), 256, 0, stream>>>(MLPb, W2b + (long)l * 131072,
                                                  fc2b + l * 256, Z,
                                                  12544, 256, 512);
    }

    k_tail_rows<<<dim3(49, 4), 256, 0, stream>>>(Z, lnfs, lnfb, poolw, poolb,
                                                 LG, MU, RSW);
    k_tail_sm<<<4, 256, 0, stream>>>(LG, MU, RSW, SB);
    k_tail_gemv<<<dim3(49, 4), 256, 0, stream>>>(Z, RSW, ACCP);
    k_tail_head<<<4, 256, 0, stream>>>(ACCP, SB, lnfs, lnfb, headw, headb, out);
}

// Round 12
// 3030.625 us; speedup vs baseline: 1.0812x; 1.0179x over previous
//
#include <hip/hip_runtime.h>
#include <hip/hip_bf16.h>
#include <cstdint>

#define SEQL 3136

typedef __attribute__((ext_vector_type(8))) short v8s;
typedef __attribute__((ext_vector_type(4))) float f32x4;
typedef __attribute__((ext_vector_type(4))) int v4i;

__device__ __forceinline__ uint16_t bf16u(float f) {
    uint32_t u = __float_as_uint(f);
    uint32_t r = u + 0x7fff + ((u >> 16) & 1);   // RNE
    return (uint16_t)(r >> 16);
}
__device__ __forceinline__ float bf2f(uint16_t b) {
    uint32_t u = ((uint32_t)b) << 16;
    return __uint_as_float(u);
}

// ---------------- merged prep: bf16 weight cvt + conv sign-weight fragment buffers ---
__global__ __launch_bounds__(256) void k_prep(const float* __restrict__ qw,
                                              const float* __restrict__ pw,
                                              const float* __restrict__ f1,
                                              const float* __restrict__ f2,
                                              const float* __restrict__ w1,
                                              const float* __restrict__ w2,
                                              const float* __restrict__ w3,
                                              uint16_t* __restrict__ dq,
                                              uint16_t* __restrict__ dp,
                                              uint16_t* __restrict__ d1,
                                              uint16_t* __restrict__ d2,
                                              uint16_t* __restrict__ w1b,
                                              uint64_t* __restrict__ wp2,
                                              uint64_t* __restrict__ wn2,
                                              uint32_t* __restrict__ wp3,
                                              uint32_t* __restrict__ wn3,
                                              uint32_t* __restrict__ w2i,
                                              uint16_t* __restrict__ w1f) {
    int gid = blockIdx.x * 256 + threadIdx.x;
    if (gid < 1376256) { dq[gid] = bf16u(qw[gid]); return; }
    if (gid < 1835008) { int i = gid - 1376256; dp[i] = bf16u(pw[i]); return; }
    if (gid < 2752512) { int i = gid - 1835008; d1[i] = bf16u(f1[i]); return; }
    if (gid < 3670016) { int i = gid - 2752512; d2[i] = bf16u(f2[i]); return; }
    if (gid < 3698688) {
        // conv1 sign weights as bf16: W1B[kw][oc][c=(ic*3+kd)*7+kh], c=63 -> 0 (legacy)
        int i = gid - 3670016;
        int c = i & 63, oc = (i >> 6) & 63, kw = i >> 12;
        uint16_t v = 0;
        if (c < 63) {
            int ic = c / 21, rem = c % 21, kd = rem / 7, kh = rem % 7;
            float w = w1[((((oc * 3 + ic) * 3 + kd) * 7 + kh) * 7) + kw];
            v = (w > 0.f) ? 0x3F80 : ((w < 0.f) ? 0xBF80 : 0);
        }
        w1b[i] = v;
        return;
    }
    if (gid < 3703392) {
        int i = gid - 3698688;
        int oc = i / 147, r = i % 147;
        uint64_t p = 0, n = 0;
        for (int ic = 0; ic < 64; ic++) {
            float v = w2[(long)oc * 9408 + (long)ic * 147 + r];
            if (v > 0.f) p |= (1ull << ic);
            else if (v < 0.f) n |= (1ull << ic);
        }
        wp2[i] = p; wn2[i] = n;
        return;
    }
    if (gid < 3703833) {
        int i = gid - 3703392;
        int oc = i / 147, r = i % 147;
        uint32_t p = 0, n = 0;
        for (int ic = 0; ic < 32; ic++) {
            float v = w3[(long)oc * 4704 + (long)ic * 147 + r];
            if (v > 0.f) p |= (1u << ic);
            else if (v < 0.f) n |= (1u << ic);
        }
        wp3[i] = p; wn3[i] = n;
        return;
    }
    if (gid < 3779097) {
        // conv2 i8 MFMA B-fragment weights: 75,264 dwords = 301,056 bytes
        int j = gid - 3703833;             // dword index
        int s4 = (j & 3) * 4;              // byte offset within the 16B lane block
        int lane = (j >> 2) & 63;
        int nt = (j >> 8) & 1;
        int r = j >> 9;                    // 0..146 = kd*49 + kh*7 + kw
        int g = lane >> 4, tl = lane & 15;
        int oc = nt * 16 + tl;
        uint32_t out = 0;
        for (int bb = 0; bb < 4; bb++) {
            int ic = g * 16 + s4 + bb;
            float w = w2[(long)oc * 9408 + (long)ic * 147 + r];
            uint32_t s8 = (w > 0.f) ? 0x01u : ((w < 0.f) ? 0xFFu : 0x00u);
            out |= s8 << (8 * bb);
        }
        w2i[j] = out;
        return;
    }
    if (gid < 3807769) {
        // conv1 bf16 MFMA B-fragments, lane-major: 28,672 u16 = 57,344 bytes
        int i = gid - 3779097;
        int e = i & 7;
        int lane = (i >> 3) & 63;
        int f = (i >> 9) & 1;
        int wn = (i >> 10) & 1;
        int ks = (i >> 11) & 1;
        int kw = i >> 12;                  // 0..6
        int tl = lane & 15, g = lane >> 4;
        int oc = wn * 32 + f * 16 + tl;
        int c = ks * 32 + g * 8 + e;
        uint16_t v = 0;
        if (c < 63) {
            int ic = c / 21, rem = c % 21, kd = rem / 7, kh = rem % 7;
            float w = w1[((((oc * 3 + ic) * 3 + kd) * 7 + kh) * 7) + kw];
            v = (w > 0.f) ? 0x3F80 : ((w < 0.f) ? 0xBF80 : 0);
        }
        w1f[i] = v;
    }
}

// ---------------- prepx: 3-way bf16 split of x into padded planes -------------------
// X3[s][b][ic][dslot 27][ih' 232][iw' 232] u16; dslot = d+1 (slot0 = zero plane);
// ih' = ih+3, iw' = iw+3; borders zero. Written as u32 (iw'-pairs).
__global__ __launch_bounds__(256) void k_prepx(const float* __restrict__ x,
                                               uint32_t* __restrict__ X3) {
    int gid = blockIdx.x * 256 + threadIdx.x;
    if (gid >= 26158464) return;
    int iwp = gid % 116;
    int t = gid / 116;
    int ihp = t % 232; t /= 232;
    int dslot = t % 27; t /= 27;
    int ic = t % 3; t /= 3;
    int b = t & 3; int s = t >> 2;
    int d = dslot - 1;
    int ih = ihp - 3;
    uint32_t out = 0;
    if (d >= 0 && (unsigned)ih < 224u) {
        const float* xp = x + ((long)(b * 3 + ic) * 27 + d) * 50176 + ih * 224;
#pragma unroll
        for (int half = 0; half < 2; half++) {
            int iw = 2 * iwp + half - 3;
            float v = ((unsigned)iw < 224u) ? xp[iw] : 0.f;
            uint16_t hi = bf16u(v);
            uint16_t o = hi;
            if (s > 0) {
                float r1 = v - bf2f(hi);
                uint16_t lo = bf16u(r1);
                o = (s == 2) ? bf16u(r1 - bf2f(lo)) : lo;
            }
            out |= ((uint32_t)o) << (16 * half);
        }
    }
    X3[gid] = out;
}

// ---------------- conv1: MFMA implicit GEMM from pre-split X3, packed u64 out --------
// Weights: double-buffered LDS staging of W1F (lane-major, conflict-free ds_read_b128),
// prefetch kw+1 before computing kw; 1 barrier per kw. obits16 aliases Wb[1] (dead in
// epilogue) -> 51.6 KB LDS. oh XCD-swizzled for L2 row reuse (FETCH 357->60MB, r9).
// NOTE: register-staged Xt pipeline (r8) spilled to scratch and regressed 2x.
// Xt stride 76 u16 is bank-optimal (38dw, gcd2); any 16B-aligned stride clusters banks.
__device__ __forceinline__ v8s ldA76(const uint16_t* Xt, int colb, int c0) {
    union { v8s v; uint2 u[2]; } t;
    const uint16_t* p = Xt + colb * 76 + c0;
    t.u[0] = *(const uint2*)p;
    t.u[1] = *(const uint2*)(p + 4);
    return t.v;
}

__global__ __launch_bounds__(256) void k_conv1m(const uint16_t* __restrict__ X3,
                                                const uint16_t* __restrict__ w1f,
                                                uint64_t* __restrict__ b1p) {
    __shared__ __align__(16) uint16_t Xt[232 * 76];   // [col][c] stride 76 (38dw, gcd2)
    __shared__ __align__(16) uint16_t Wb[2][4096];    // dbuf weights; Wb[1] = obits alias
    int tid = threadIdx.x;
    int bidx = blockIdx.x;
    int oh = (bidx & 7) * 28 + (bidx >> 3);           // XCD-contiguous oh (224 = 8*28)
    int od = blockIdx.y, b = blockIdx.z;
    int lane = tid & 63, wv = tid >> 6;
    int wm = wv >> 1, wn = wv & 1;
    int tl = lane & 15, g = lane >> 4;

    f32x4 acc[7][2];
#pragma unroll
    for (int mt = 0; mt < 7; mt++) {
        acc[mt][0] = (f32x4){0.f, 0.f, 0.f, 0.f};
        acc[mt][1] = (f32x4){0.f, 0.f, 0.f, 0.f};
    }

    for (int s = 0; s < 3; s++) {
        // Xt/Wb[0] writable: s=0 nothing read yet; s>0 covered by final kw barrier of s-1.
        if (tid < 232) {
            const uint16_t* Xb = X3 + ((long)(s * 4 + b) * 81 + (long)od * 3) * 53824
                               + oh * 232 + tid;
#pragma unroll
            for (int cp = 0; cp < 32; cp++) {
                const int c0 = 2 * cp, c1 = c0 + 1;
                uint32_t v0 = 0, v1 = 0;
                if (c0 < 63) {
                    const int ickd = c0 / 7, kh = c0 % 7;
                    const int ic = ickd / 3, kd = ickd % 3;
                    v0 = Xb[(long)(ic * 27 + kd) * 53824 + kh * 232];
                }
                if (c1 < 63) {
                    const int ickd = c1 / 7, kh = c1 % 7;
                    const int ic = ickd / 3, kd = ickd % 3;
                    v1 = Xb[(long)(ic * 27 + kd) * 53824 + kh * 232];
                }
                *(uint32_t*)&Xt[tid * 76 + c0] = v0 | (v1 << 16);
            }
        }
        {   // stage kw=0 weights into Wb[0] (8 KB, coalesced uint4)
            const uint4* src = (const uint4*)w1f;
            uint4* dst = (uint4*)Wb[0];
            dst[tid] = src[tid];
            dst[256 + tid] = src[256 + tid];
        }
        __syncthreads();   // Xt + Wb[0] visible
        for (int kw = 0; kw < 7; kw++) {
            int cur = kw & 1;
            if (kw < 6) {
                // prefetch kw+1 into the other buffer; latency hides under MFMAs
                const uint4* src = (const uint4*)(w1f + (kw + 1) * 4096);
                uint4* dst = (uint4*)Wb[cur ^ 1];
                dst[tid] = src[tid];
                dst[256 + tid] = src[256 + tid];
            }
#pragma unroll
            for (int ks = 0; ks < 2; ks++) {
                // lane-major: ds_read_b128 at lane*16, conflict-free
                const uint16_t* wfb = &Wb[cur][((ks * 2 + wn) * 2) * 512 + lane * 8];
                v8s b0 = *(const v8s*)wfb;
                v8s b1 = *(const v8s*)(wfb + 512);
#pragma unroll
                for (int mt = 0; mt < 7; mt++) {
                    int colb = (wm * 7 + mt) * 16 + tl + kw;   // Xt index = xcol+3
                    v8s a = ldA76(Xt, colb, ks * 32 + g * 8);
                    acc[mt][0] = __builtin_amdgcn_mfma_f32_16x16x32_bf16(a, b0, acc[mt][0], 0, 0, 0);
                    acc[mt][1] = __builtin_amdgcn_mfma_f32_16x16x32_bf16(a, b1, acc[mt][1], 0, 0, 0);
                }
            }
            __syncthreads();   // Wb[cur^1] written+visible; Wb[cur] reads done
        }
    }
    // epilogue: ballot -> 16-bit oc pieces (obits aliases Wb[1]; all Wb reads done)
    uint16_t* obits16 = (uint16_t*)Wb[1];
#pragma unroll
    for (int mt = 0; mt < 7; mt++)
#pragma unroll
        for (int nt = 0; nt < 2; nt++)
#pragma unroll
            for (int r = 0; r < 4; r++) {
                unsigned long long mask = __ballot(acc[mt][nt][r] > 0.f);
                if (tl == 0) {
                    int ow = (wm * 7 + mt) * 16 + g * 4 + r;
                    obits16[ow * 4 + wn * 2 + nt] = (uint16_t)(mask >> (g * 16));
                }
            }
    __syncthreads();
    if (tid < 224) {
        uint64_t w = (uint64_t)obits16[tid * 4]
                   | ((uint64_t)obits16[tid * 4 + 1] << 16)
                   | ((uint64_t)obits16[tid * 4 + 2] << 32)
                   | ((uint64_t)obits16[tid * 4 + 3] << 48);
        b1p[(((long)b * 9 + od) * 224 + oh) * 224 + tid] = w;
    }
}

// ---------------- conv2: i8 MFMA implicit GEMM over packed bitplanes -----------------
__global__ __launch_bounds__(256) void k_conv2m(const uint64_t* __restrict__ bp1,
                                                const uint8_t* __restrict__ w2i,
                                                uint32_t* __restrict__ b2p) {
    __shared__ __align__(16) uint64_t xs[21 * 232];       // 38,976 B  packed input rows
    __shared__ uint16_t obits16[224 * 2];
    int tid = threadIdx.x;
    int bidx = blockIdx.x;
    int oh = (bidx & 7) * 28 + (bidx >> 3);               // XCD-contiguous oh
    int od = blockIdx.y, b = blockIdx.z;
    int lane = tid & 63, wv = tid >> 6;
    int tl = lane & 15, g = lane >> 4;
    int g2 = g >> 1, sh = (g & 1) * 16;

    // stage all 21 (kd,kh) rows of packed u64 bits, zero-padded borders
    for (int i = tid; i < 21 * 232; i += 256) {
        int row = i / 232, wp = i - row * 232;
        int kd = row / 7, kh = row - kd * 7;
        int d = od * 3 - 1 + kd;
        int h = oh - 3 + kh;
        int w = wp - 3;
        uint64_t v = 0;
        if ((unsigned)d < 9u && (unsigned)h < 224u && (unsigned)w < 224u)
            v = bp1[(((long)b * 9 + d) * 224 + h) * 224 + w];
        xs[i] = v;
    }

    int nmt = (wv < 2) ? 4 : 3;   // waves 0,1: 4 M-tiles; waves 2,3: 3 M-tiles
    v4i acc[4][2];
#pragma unroll
    for (int mi = 0; mi < 4; mi++) {
        acc[mi][0] = (v4i){0, 0, 0, 0};
        acc[mi][1] = (v4i){0, 0, 0, 0};
    }
    __syncthreads();   // xs visible

    for (int row = 0; row < 21; row++) {
        const uint8_t* wr = w2i + (long)row * 14336;      // L2-resident fragments
        const uint32_t* x32 = (const uint32_t*)&xs[row * 232];
#pragma unroll
        for (int kw = 0; kw < 7; kw++) {
            v4i bf0 = *(const v4i*)&wr[(kw * 2 + 0) * 1024 + lane * 16];
            v4i bf1 = *(const v4i*)&wr[(kw * 2 + 1) * 1024 + lane * 16];
#pragma unroll
            for (int mi = 0; mi < 4; mi++) {
                if (mi < nmt) {
                    int mt = wv + mi * 4;
                    // 16 ic bits for this lane's k-chunk (g*16..+15) at position ow+kw
                    uint32_t c = x32[(mt * 16 + tl + kw) * 2 + g2] >> sh;
                    v4i a;
#pragma unroll
                    for (int j = 0; j < 4; j++) {
                        uint32_t d4 = (c >> (4 * j)) & 0xFu;
                        a[j] = (int)((d4 * 0x204081u) & 0x01010101u);
                    }
                    acc[mi][0] = __builtin_amdgcn_mfma_i32_16x16x64_i8(a, bf0, acc[mi][0], 0, 0, 0);
                    acc[mi][1] = __builtin_amdgcn_mfma_i32_16x16x64_i8(a, bf1, acc[mi][1], 0, 0, 0);
                }
            }
        }
    }
    // epilogue: sign bits via ballot, pack 32 oc bits per ow
#pragma unroll
    for (int mi = 0; mi < 4; mi++) {
        if (mi < nmt) {
            int mt = wv + mi * 4;
#pragma unroll
            for (int nt = 0; nt < 2; nt++)
#pragma unroll
                for (int r = 0; r < 4; r++) {
                    unsigned long long mask = __ballot(acc[mi][nt][r] > 0);
                    if (tl == 0)
                        obits16[(mt * 16 + g * 4 + r) * 2 + nt] = (uint16_t)(mask >> (g * 16));
                }
        }
    }
    __syncthreads();
    if (tid < 224) {
        uint32_t wo = (uint32_t)obits16[tid * 2] | ((uint32_t)obits16[tid * 2 + 1] << 16);
        b2p[(((long)b * 3 + od) * 224 + oh) * 224 + tid] = wo;
    }
}

// conv3 via popcount -> fp32 relu count
__global__ __launch_bounds__(256) void k_conv3(const uint32_t* __restrict__ bp2,
                                               const uint32_t* __restrict__ wp,
                                               const uint32_t* __restrict__ wn,
                                               float* __restrict__ h3) {
    int gid = blockIdx.x * 256 + threadIdx.x;  // 602,112
    int q = gid;
    int ow = q % 224; q /= 224;
    int oh = q % 224; q /= 224;
    int oc = q % 3;   int b = q / 3;
    int acc = 0;
    for (int kd = 0; kd < 3; kd++) {
        int d = kd - 1;
        if ((unsigned)d >= 3u) continue;
        for (int kh = 0; kh < 7; kh++) {
            int h = oh - 3 + kh;
            if ((unsigned)h >= 224u) continue;
            const uint32_t* bp = bp2 + ((long)(b * 3 + d) * 224 + h) * 224;
            const uint32_t* mp = wp + ((oc * 3 + kd) * 7 + kh) * 7;
            const uint32_t* mn = wn + ((oc * 3 + kd) * 7 + kh) * 7;
#pragma unroll
            for (int kw = 0; kw < 7; kw++) {
                int w = ow - 3 + kw;
                if ((unsigned)w < 224u) {
                    uint32_t bits = bp[w];
                    acc += __popc(bits & mp[kw]) - __popc(bits & mn[kw]);
                }
            }
        }
    }
    h3[gid] = fmaxf((float)acc, 0.f);
}

// ---------------- tokenizer conv; tok layout [b][h][w][c] ----------------
__global__ __launch_bounds__(256) void k_tok(const float* __restrict__ h3,
                                             const float* __restrict__ wt,
                                             float* __restrict__ tok) {
    __shared__ float xs[3 * 7 * 232];
    int tid = threadIdx.x;
    int oh = blockIdx.x, b = blockIdx.y;
    for (int i = tid; i < 3 * 7 * 232; i += 256) {
        int col = i % 232; int t = i / 232;
        int kh = t % 7; int ic = t / 7;
        int ih = oh * 2 - 3 + kh;
        int iw = col - 3;
        float v = 0.f;
        if ((unsigned)ih < 224u && (unsigned)iw < 224u)
            v = h3[((long)(b * 3 + ic) * 50176) + ih * 224 + iw];
        xs[i] = v;
    }
    __syncthreads();
    int oc = tid;
    float* obase = tok + ((long)(b * 112 + oh) * 112) * 256 + oc;
    for (int chunk = 0; chunk < 4; chunk++) {
        int ow0 = chunk * 28;
        float acc[28];
#pragma unroll
        for (int o2 = 0; o2 < 28; o2++) acc[o2] = 0.f;
        for (int ic = 0; ic < 3; ic++) {
#pragma unroll
            for (int kh = 0; kh < 7; kh++) {
                const float* row = &xs[(ic * 7 + kh) * 232 + ow0 * 2];
                float xv[61];
#pragma unroll
                for (int t = 0; t < 61; t++) xv[t] = row[t];
                const float* wr = wt + (oc * 3 + ic) * 49 + kh * 7;
                float w[7];
#pragma unroll
                for (int kw = 0; kw < 7; kw++) w[kw] = wr[kw];
#pragma unroll
                for (int kw = 0; kw < 7; kw++)
#pragma unroll
                    for (int o2 = 0; o2 < 28; o2++)
                        acc[o2] = fmaf(w[kw], xv[2 * o2 + kw], acc[o2]);
            }
        }
#pragma unroll
        for (int o2 = 0; o2 < 28; o2++)
            obase[(long)(ow0 + o2) * 256] = fmaxf(acc[o2], 0.f);
    }
}

// maxpool 3x3 s2 p1 + pos_emb
__global__ __launch_bounds__(256) void k_pool_z(const float* __restrict__ tok,
                                                const float* __restrict__ pos,
                                                float* __restrict__ z) {
    int gid = blockIdx.x * 256 + threadIdx.x;
    int c = gid & 255;
    int n = (gid >> 8) % SEQL;
    int b = gid / (256 * SEQL);
    int oh = n / 56, ow = n % 56;
    const float* tp = tok + ((long)b * 112 * 112) * 256 + c;
    float m = -1e30f;
#pragma unroll
    for (int kh = 0; kh < 3; kh++) {
        int h = oh * 2 - 1 + kh;
        if ((unsigned)h >= 112u) continue;
#pragma unroll
        for (int kw = 0; kw < 3; kw++) {
            int w = ow * 2 - 1 + kw;
            if ((unsigned)w < 112u) m = fmaxf(m, tp[(long)(h * 112 + w) * 256]);
        }
    }
    z[gid] = m + pos[n * 256 + c];
}

// ---------------- GEMM with fused layernorm on A (A = LN(Z) rows) ----------------
// When dovt!=0 (qkv projection), the Q columns (col<256) are pre-scaled by 0.125
// (exact power-of-2) so k_flash skips the softmax input scaling.
__global__ __launch_bounds__(256) void k_gemm_ln(const float* __restrict__ Z,
                                                 const uint16_t* __restrict__ W,
                                                 const float* __restrict__ lns,
                                                 const float* __restrict__ lnb,
                                                 const float* __restrict__ bias,
                                                 uint16_t* __restrict__ C,
                                                 uint16_t* __restrict__ VT,
                                                 int N, int dogelu, int dovt) {
    __shared__ uint16_t As[128 * 40], Bs[128 * 40];
    __shared__ float mu[128], rsd[128];
    int tid = threadIdx.x;
    int lane = tid & 63, wave = tid >> 6;
    int wm = wave >> 1, wn = wave & 1;
    int m0 = blockIdx.y * 128, n0 = blockIdx.x * 128;
    {
        int row = tid >> 1, hf = tid & 1;
        const float* zr = Z + (long)(m0 + row) * 256 + hf * 128;
        float s = 0.f, sq = 0.f;
        for (int i = 0; i < 128; i++) { float v = zr[i]; s += v; sq += v * v; }
        s += __shfl_xor(s, 1); sq += __shfl_xor(sq, 1);
        if (hf == 0) {
            float m = s * (1.0f / 256.0f);
            mu[row] = m;
            rsd[row] = rsqrtf(sq * (1.0f / 256.0f) - m * m + 1e-5f);
        }
    }
    f32x4 acc[4][4];
#pragma unroll
    for (int i = 0; i < 4; i++)
#pragma unroll
        for (int j = 0; j < 4; j++) acc[i][j] = (f32x4){0.f, 0.f, 0.f, 0.f};
    int rl = lane & 15, kq = (lane >> 4) * 8;
    for (int k0 = 0; k0 < 256; k0 += 32) {
        __syncthreads();
#pragma unroll
        for (int c2 = 0; c2 < 16; c2++) {
            int idx = c2 * 256 + tid;
            int col = idx & 31, row = idx >> 5;
            float v = Z[(long)(m0 + row) * 256 + k0 + col];
            v = (v - mu[row]) * rsd[row] * lns[k0 + col] + lnb[k0 + col];
            As[row * 40 + col] = bf16u(v);
        }
#pragma unroll
        for (int c = 0; c < 2; c++) {
            int idx = c * 256 + tid;
            int row = idx >> 2, k8 = (idx & 3) * 8;
            *(uint4*)&Bs[row * 40 + k8] = *(const uint4*)&W[(long)(n0 + row) * 256 + k0 + k8];
        }
        __syncthreads();
        v8s a[4], bb[4];
#pragma unroll
        for (int i = 0; i < 4; i++) a[i] = *(const v8s*)&As[(wm * 64 + i * 16 + rl) * 40 + kq];
#pragma unroll
        for (int j = 0; j < 4; j++) bb[j] = *(const v8s*)&Bs[(wn * 64 + j * 16 + rl) * 40 + kq];
#pragma unroll
        for (int i = 0; i < 4; i++)
#pragma unroll
            for (int j = 0; j < 4; j++)
                acc[i][j] = __builtin_amdgcn_mfma_f32_16x16x32_bf16(a[i], bb[j], acc[i][j], 0, 0, 0);
    }
    int rq = (lane >> 4) * 4;
    bool vt = (dovt != 0) && (n0 >= 512);
#pragma unroll
    for (int i = 0; i < 4; i++) {
#pragma unroll
        for (int j = 0; j < 4; j++) {
            int col = n0 + wn * 64 + j * 16 + rl;
            float bval = bias[col];
#pragma unroll
            for (int r = 0; r < 4; r++) {
                int row = m0 + wm * 64 + i * 16 + rq + r;
                float v = acc[i][j][r] + bval;
                if (dogelu) v = 0.5f * v * (1.0f + erff(v * 0.70710678118654752f));
                if (dovt != 0 && col < 256) v *= 0.125f;   // pre-scale Q (exact)
                if (vt) {
                    int hv = col - 512;
                    int h = hv >> 6, d = hv & 63;
                    int bb2 = row / SEQL, nn = row - bb2 * SEQL;
                    VT[((long)(bb2 * 4 + h) * 64 + d) * SEQL + nn] = bf16u(v);
                } else {
                    C[(long)row * N + col] = bf16u(v);
                }
            }
        }
    }
}

// ---------------- plain bf16 GEMM (A bf16), resid fp32 += ----------------
__global__ __launch_bounds__(256) void k_gemm(const uint16_t* __restrict__ A,
                                              const uint16_t* __restrict__ W,
                                              const float* __restrict__ bias,
                                              float* __restrict__ C,
                                              int M, int N, int K) {
    __shared__ uint16_t As[128 * 40], Bs[128 * 40];
    int tid = threadIdx.x;
    int lane = tid & 63, wave = tid >> 6;
    int wm = wave >> 1, wn = wave & 1;
    int m0 = blockIdx.y * 128, n0 = blockIdx.x * 128;
    f32x4 acc[4][4];
#pragma unroll
    for (int i = 0; i < 4; i++)
#pragma unroll
        for (int j = 0; j < 4; j++) acc[i][j] = (f32x4){0.f, 0.f, 0.f, 0.f};
    int rl = lane & 15, kq = (lane >> 4) * 8;
    for (int k0 = 0; k0 < K; k0 += 32) {
        __syncthreads();
#pragma unroll
        for (int c = 0; c < 2; c++) {
            int idx = c * 256 + tid;
            int row = idx >> 2, k8 = (idx & 3) * 8;
            *(uint4*)&As[row * 40 + k8] = *(const uint4*)&A[(long)(m0 + row) * K + k0 + k8];
            *(uint4*)&Bs[row * 40 + k8] = *(const uint4*)&W[(long)(n0 + row) * K + k0 + k8];
        }
        __syncthreads();
        v8s a[4], bb[4];
#pragma unroll
        for (int i = 0; i < 4; i++) a[i] = *(const v8s*)&As[(wm * 64 + i * 16 + rl) * 40 + kq];
#pragma unroll
        for (int j = 0; j < 4; j++) bb[j] = *(const v8s*)&Bs[(wn * 64 + j * 16 + rl) * 40 + kq];
#pragma unroll
        for (int i = 0; i < 4; i++)
#pragma unroll
            for (int j = 0; j < 4; j++)
                acc[i][j] = __builtin_amdgcn_mfma_f32_16x16x32_bf16(a[i], bb[j], acc[i][j], 0, 0, 0);
    }
    int rq = (lane >> 4) * 4;
#pragma unroll
    for (int i = 0; i < 4; i++) {
#pragma unroll
        for (int j = 0; j < 4; j++) {
            int col = n0 + wn * 64 + j * 16 + rl;
            float bval = bias[col];
#pragma unroll
            for (int r = 0; r < 4; r++) {
                int row = m0 + wm * 64 + i * 16 + rq + r;
                C[(long)row * N + col] += acc[i][j][r] + bval;
            }
        }
    }
}

// ---------------- bf16 GEMM, BM=128 x BN=64 tiles (N=256: grid (4,98)=392 blocks) ---
__global__ __launch_bounds__(256) void k_gemm64(const uint16_t* __restrict__ A,
                                                const uint16_t* __restrict__ W,
                                                const float* __restrict__ bias,
                                                float* __restrict__ C,
                                                int M, int N, int K) {
    __shared__ uint16_t As[128 * 40], Bs[64 * 40];
    int tid = threadIdx.x;
    int lane = tid & 63, wave = tid >> 6;
    int wm = wave >> 1, wn = wave & 1;
    int m0 = blockIdx.y * 128, n0 = blockIdx.x * 64;
    f32x4 acc[4][2];
#pragma unroll
    for (int i = 0; i < 4; i++)
#pragma unroll
        for (int j = 0; j < 2; j++) acc[i][j] = (f32x4){0.f, 0.f, 0.f, 0.f};
    int rl = lane & 15, kq = (lane >> 4) * 8;
    for (int k0 = 0; k0 < K; k0 += 32) {
        __syncthreads();
#pragma unroll
        for (int c = 0; c < 2; c++) {
            int idx = c * 256 + tid;
            int row = idx >> 2, k8 = (idx & 3) * 8;
            *(uint4*)&As[row * 40 + k8] = *(const uint4*)&A[(long)(m0 + row) * K + k0 + k8];
        }
        {
            int row = tid >> 2, k8 = (tid & 3) * 8;
            *(uint4*)&Bs[row * 40 + k8] = *(const uint4*)&W[(long)(n0 + row) * K + k0 + k8];
        }
        __syncthreads();
        v8s a[4], bb[2];
#pragma unroll
        for (int i = 0; i < 4; i++) a[i] = *(const v8s*)&As[(wm * 64 + i * 16 + rl) * 40 + kq];
#pragma unroll
        for (int j = 0; j < 2; j++) bb[j] = *(const v8s*)&Bs[(wn * 32 + j * 16 + rl) * 40 + kq];
#pragma unroll
        for (int i = 0; i < 4; i++)
#pragma unroll
            for (int j = 0; j < 2; j++)
                acc[i][j] = __builtin_amdgcn_mfma_f32_16x16x32_bf16(a[i], bb[j], acc[i][j], 0, 0, 0);
    }
    int rq = (lane >> 4) * 4;
#pragma unroll
    for (int i = 0; i < 4; i++) {
#pragma unroll
        for (int j = 0; j < 2; j++) {
            int col = n0 + wn * 32 + j * 16 + rl;
            float bval = bias[col];
#pragma unroll
            for (int r = 0; r < 4; r++) {
                int row = m0 + wm * 64 + i * 16 + rq + r;
                C[(long)row * N + col] += acc[i][j][r] + bval;
            }
        }
    }
}

// ---------------- flash attention, bf16 MFMA, register-prefetched K/V staging ------
// Q pre-scaled by 0.125 in k_gemm_ln. K/V tile kt+1 is loaded into 4 uint4 REGISTERS
// right after the staging barrier, so HBM/L2 latency hides under compute(kt); the
// inter-barrier region is only 4 ds_write_b128. LDS stays 36,864 B (4 blocks/CU —
// r10 showed the LDS-dbuf variant at 46 KB lost a block/CU and regressed).
__global__ __launch_bounds__(256) void k_flash(const uint16_t* __restrict__ G,
                                               const uint16_t* __restrict__ VT,
                                               uint16_t* __restrict__ o) {
    __shared__ __align__(16) uint32_t Qs[64 * 36], Ks[64 * 36], Vt[64 * 36];
    __shared__ __align__(16) uint16_t Ps[64 * 72];
    int tid = threadIdx.x;
    int lane = tid & 63, wv = tid >> 6;
    int qt = blockIdx.x, h = blockIdx.y, b = blockIdx.z;
    long base = (long)b * SEQL * 768 + h * 64;
    long vtbase = ((long)(b * 4 + h) * 64) * SEQL;
#pragma unroll
    for (int it = 0; it < 2; it++) {
        int idx = it * 256 + tid;
        int q8 = idx & 7, r = idx >> 3;
        *(uint4*)&Qs[r * 36 + q8 * 4] = *(const uint4*)&G[base + (long)(qt * 64 + r) * 768 + q8 * 8];
    }
    // per-thread K/V chunk coordinates (2 chunks each)
    int kr_r0 = tid >> 3, kr_q0 = tid & 7;            // idx0 = tid
    int kr_r1 = (256 + tid) >> 3, kr_q1 = tid & 7;    // idx1 = 256+tid (low 3 bits same)
    // prefetch tile 0 into registers
    uint4 kreg0 = *(const uint4*)&G[base + (long)kr_r0 * 768 + 256 + kr_q0 * 8];
    uint4 kreg1 = *(const uint4*)&G[base + (long)kr_r1 * 768 + 256 + kr_q1 * 8];
    uint4 vreg0 = *(const uint4*)&VT[vtbase + (long)kr_r0 * SEQL + kr_q0 * 8];
    uint4 vreg1 = *(const uint4*)&VT[vtbase + (long)kr_r1 * SEQL + kr_q1 * 8];
    int g = lane >> 4, tl = lane & 15;
    int qr0 = wv * 16;
    __syncthreads();
    v8s aq[2];
#pragma unroll
    for (int ks = 0; ks < 2; ks++)
        aq[ks] = *(const v8s*)&Qs[(qr0 + tl) * 36 + ks * 16 + g * 4];

    float m_[4], l_[4];
    f32x4 ov[4];
#pragma unroll
    for (int r = 0; r < 4; r++) { m_[r] = -1e30f; l_[r] = 0.f; }
#pragma unroll
    for (int j = 0; j < 4; j++) ov[j] = (f32x4){0.f, 0.f, 0.f, 0.f};

    for (int kt = 0; kt < 49; kt++) {
        __syncthreads();   // prior compute's Ks/Vt/Ps reads done
        // write the register-staged tile kt (4x ds_write_b128, fast)
        *(uint4*)&Ks[kr_r0 * 36 + kr_q0 * 4] = kreg0;
        *(uint4*)&Ks[kr_r1 * 36 + kr_q1 * 4] = kreg1;
        *(uint4*)&Vt[kr_r0 * 36 + kr_q0 * 4] = vreg0;
        *(uint4*)&Vt[kr_r1 * 36 + kr_q1 * 4] = vreg1;
        __syncthreads();   // tile kt visible
        if (kt < 48) {     // issue tile kt+1 loads; latency hides under compute below
            int nk = kt + 1;
            kreg0 = *(const uint4*)&G[base + (long)(nk * 64 + kr_r0) * 768 + 256 + kr_q0 * 8];
            kreg1 = *(const uint4*)&G[base + (long)(nk * 64 + kr_r1) * 768 + 256 + kr_q1 * 8];
            vreg0 = *(const uint4*)&VT[vtbase + (long)kr_r0 * SEQL + nk * 64 + kr_q0 * 8];
            vreg1 = *(const uint4*)&VT[vtbase + (long)kr_r1 * SEQL + nk * 64 + kr_q1 * 8];
        }
        f32x4 s[4];
#pragma unroll
        for (int j = 0; j < 4; j++) s[j] = (f32x4){0.f, 0.f, 0.f, 0.f};
#pragma unroll
        for (int ks = 0; ks < 2; ks++) {
#pragma unroll
            for (int j = 0; j < 4; j++) {
                v8s bk = *(const v8s*)&Ks[(j * 16 + tl) * 36 + ks * 16 + g * 4];
                s[j] = __builtin_amdgcn_mfma_f32_16x16x32_bf16(aq[ks], bk, s[j], 0, 0, 0);
            }
        }
        float alpha[4];
#pragma unroll
        for (int r = 0; r < 4; r++) {
            float s0 = s[0][r], s1 = s[1][r];
            float s2 = s[2][r], s3 = s[3][r];
            float mx = fmaxf(fmaxf(s0, s1), fmaxf(s2, s3));
#pragma unroll
            for (int off = 1; off < 16; off <<= 1) mx = fmaxf(mx, __shfl_xor(mx, off));
            float nm = fmaxf(m_[r], mx);
            alpha[r] = __expf(m_[r] - nm);
            float rs = 0.f;
#pragma unroll
            for (int j = 0; j < 4; j++) {
                float p = __expf(s[j][r] - nm);
                s[j][r] = p; rs += p;
            }
#pragma unroll
            for (int off = 1; off < 16; off <<= 1) rs += __shfl_xor(rs, off);
            l_[r] = l_[r] * alpha[r] + rs;
            m_[r] = nm;
        }
#pragma unroll
        for (int j = 0; j < 4; j++)
#pragma unroll
            for (int r = 0; r < 4; r++) ov[j][r] *= alpha[r];
#pragma unroll
        for (int j = 0; j < 4; j++)
#pragma unroll
            for (int r = 0; r < 4; r++)
                Ps[(qr0 + g * 4 + r) * 72 + j * 16 + tl] = bf16u(s[j][r]);
#pragma unroll
        for (int ks = 0; ks < 2; ks++) {
            v8s ap = *(const v8s*)&Ps[(qr0 + tl) * 72 + ks * 32 + g * 8];
#pragma unroll
            for (int jd = 0; jd < 4; jd++) {
                v8s bv = *(const v8s*)&Vt[(jd * 16 + tl) * 36 + ks * 16 + g * 4];
                ov[jd] = __builtin_amdgcn_mfma_f32_16x16x32_bf16(ap, bv, ov[jd], 0, 0, 0);
            }
        }
    }
    long ob = ((long)b * SEQL + qt * 64) * 256 + h * 64;
#pragma unroll
    for (int r = 0; r < 4; r++) {
        float inv = 1.0f / l_[r];
        int row = qr0 + g * 4 + r;
#pragma unroll
        for (int jd = 0; jd < 4; jd++)
            o[ob + (long)row * 256 + jd * 16 + tl] = bf16u(ov[jd][r] * inv);
    }
}

// ---------------- parallel tail ----------------------------------------------------
// Phase 1: per-row LN stats + pool logit (grid 49 x 4; 196 blocks)
__global__ __launch_bounds__(256) void k_tail_rows(const float* __restrict__ Z,
                                                   const float* __restrict__ g,
                                                   const float* __restrict__ be,
                                                   const float* __restrict__ pw,
                                                   const float* __restrict__ pb,
                                                   float* __restrict__ LG,
                                                   float* __restrict__ MU,
                                                   float* __restrict__ RS) {
    int tid = threadIdx.x;
    int wv = tid >> 6, lane = tid & 63;
    int b = blockIdx.y;
    int r0 = blockIdx.x * 64;
    const float* Zb = Z + (long)b * SEQL * 256;
    for (int r = r0 + wv; r < r0 + 64; r += 4) {
        const float* xr = Zb + (long)r * 256;
        float v0 = xr[lane], v1 = xr[lane + 64], v2 = xr[lane + 128], v3 = xr[lane + 192];
        float s = v0 + v1 + v2 + v3;
#pragma unroll
        for (int off = 1; off < 64; off <<= 1) s += __shfl_xor(s, off);
        float mean = s * (1.0f / 256.0f);
        float d0 = v0 - mean, d1 = v1 - mean, d2 = v2 - mean, d3 = v3 - mean;
        float sq = d0 * d0 + d1 * d1 + d2 * d2 + d3 * d3;
#pragma unroll
        for (int off = 1; off < 64; off <<= 1) sq += __shfl_xor(sq, off);
        float rs_ = rsqrtf(sq * (1.0f / 256.0f) + 1e-5f);
        float a = (d0 * rs_ * g[lane] + be[lane]) * pw[lane]
                + (d1 * rs_ * g[lane + 64] + be[lane + 64]) * pw[lane + 64]
                + (d2 * rs_ * g[lane + 128] + be[lane + 128]) * pw[lane + 128]
                + (d3 * rs_ * g[lane + 192] + be[lane + 192]) * pw[lane + 192];
#pragma unroll
        for (int off = 1; off < 64; off <<= 1) a += __shfl_xor(a, off);
        if (lane == 0) {
            LG[b * SEQL + r] = a + pb[0];
            MU[b * SEQL + r] = mean;
            RS[b * SEQL + r] = rs_;
        }
    }
}

// Phase 2: softmax over tokens; fold p*rs in place; sB = sum p*mu*rs (grid 4)
__global__ __launch_bounds__(256) void k_tail_sm(const float* __restrict__ LG,
                                                 const float* __restrict__ MU,
                                                 float* __restrict__ RSW,
                                                 float* __restrict__ SB) {
    __shared__ float red[256];
    int b = blockIdx.x, tid = threadIdx.x;
    const float* lg = LG + (long)b * SEQL;
    const float* mu = MU + (long)b * SEQL;
    float* rw = RSW + (long)b * SEQL;
    float m = -1e30f;
    for (int i = tid; i < SEQL; i += 256) m = fmaxf(m, lg[i]);
    red[tid] = m; __syncthreads();
    for (int s = 128; s > 0; s >>= 1) {
        if (tid < s) red[tid] = fmaxf(red[tid], red[tid + s]);
        __syncthreads();
    }
    float M = red[0]; __syncthreads();
    float sum = 0.f;
    for (int i = tid; i < SEQL; i += 256) sum += expf(lg[i] - M);
    red[tid] = sum; __syncthreads();
    for (int s = 128; s > 0; s >>= 1) {
        if (tid < s) red[tid] += red[tid + s];
        __syncthreads();
    }
    float inv = 1.0f / red[0];
    __syncthreads();
    float pB = 0.f;
    for (int i = tid; i < SEQL; i += 256) {
        float p = expf(lg[i] - M) * inv;
        float rs_ = rw[i];
        pB += p * mu[i] * rs_;
        rw[i] = p * rs_;
    }
    red[tid] = pB; __syncthreads();
    for (int s = 128; s > 0; s >>= 1) {
        if (tid < s) red[tid] += red[tid + s];
        __syncthreads();
    }
    if (tid == 0) SB[b] = red[0];
}

// Phase 3: partial weighted column-sum acc[d] = sum_n (p*rs)[n] * Z[n][d] (grid 49 x 4)
__global__ __launch_bounds__(256) void k_tail_gemv(const float* __restrict__ Z,
                                                   const float* __restrict__ RSW,
                                                   float* __restrict__ ACCP) {
    __shared__ float wsm[64];
    int b = blockIdx.y, tid = threadIdx.x;
    int n0 = blockIdx.x * 64;
    if (tid < 64) wsm[tid] = RSW[(long)b * SEQL + n0 + tid];
    __syncthreads();
    const float* Zb = Z + ((long)b * SEQL + n0) * 256;
    float acc = 0.f;
#pragma unroll 8
    for (int n = 0; n < 64; n++) acc = fmaf(wsm[n], Zb[(long)n * 256 + tid], acc);
    ACCP[((long)blockIdx.x * 4 + b) * 256 + tid] = acc;
}

// Phase 4: finalize pooled + classifier head (grid 4)
__global__ __launch_bounds__(256) void k_tail_head(const float* __restrict__ ACCP,
                                                   const float* __restrict__ SB,
                                                   const float* __restrict__ g,
                                                   const float* __restrict__ be,
                                                   const float* __restrict__ hw,
                                                   const float* __restrict__ hb,
                                                   float* __restrict__ out) {
    __shared__ float pooled[256];
    int b = blockIdx.x, tid = threadIdx.x;
    float s = 0.f;
    for (int c = 0; c < 49; c++) s += ACCP[((long)c * 4 + b) * 256 + tid];
    pooled[tid] = g[tid] * (s - SB[b]) + be[tid];
    __syncthreads();
    if (tid < 101) {
        float a = hb[tid];
        for (int d = 0; d < 256; d++) a = fmaf(pooled[d], hw[tid * 256 + d], a);
        out[b * 101 + tid] = a;
    }
}

// ---------------------------------------------------------------------------
extern "C" void kernel_launch(void* const* d_in, const int* in_sizes, int n_in,
                              void* d_out, int out_size, void* d_ws, size_t ws_size,
                              hipStream_t stream) {
    (void)in_sizes; (void)n_in; (void)out_size; (void)ws_size;
    const float* x     = (const float*)d_in[0];
    const float* w1    = (const float*)d_in[1];
    const float* w2    = (const float*)d_in[2];
    const float* w3    = (const float*)d_in[3];
    const float* tokw  = (const float*)d_in[4];
    const float* pos   = (const float*)d_in[5];
    const float* ln1s  = (const float*)d_in[6];
    const float* ln1b  = (const float*)d_in[7];
    const float* qkvw  = (const float*)d_in[8];
    const float* qkvb  = (const float*)d_in[9];
    const float* projw = (const float*)d_in[10];
    const float* projb = (const float*)d_in[11];
    const float* ln2s  = (const float*)d_in[12];
    const float* ln2b  = (const float*)d_in[13];
    const float* fc1w  = (const float*)d_in[14];
    const float* fc1b  = (const float*)d_in[15];
    const float* fc2w  = (const float*)d_in[16];
    const float* fc2b  = (const float*)d_in[17];
    const float* lnfs  = (const float*)d_in[18];
    const float* lnfb  = (const float*)d_in[19];
    const float* poolw = (const float*)d_in[20];
    const float* poolb = (const float*)d_in[21];
    const float* headw = (const float*)d_in[22];
    const float* headb = (const float*)d_in[23];
    float* out = (float*)d_out;
    char* ws = (char*)d_ws;

    uint64_t* B1P = (uint64_t*)(ws + 0);                  // 14,450,688
    uint32_t* B2P = (uint32_t*)(ws + 14450688);           //  2,408,448
    float*    H3  = (float*)(ws + 16859136);              //  2,408,448
    uint16_t* W1B = (uint16_t*)(ws + 19267584);           //     57,344 (legacy layout)
    uint64_t* WP2 = (uint64_t*)(ws + 19324928);           //     37,632 (legacy, unused)
    uint64_t* WN2 = (uint64_t*)(ws + 19362560);           //     37,632 (legacy, unused)
    uint32_t* WP3 = (uint32_t*)(ws + 19400192);           //      2,048
    uint32_t* WN3 = (uint32_t*)(ws + 19402240);           //      2,048
    uint16_t* WQb = (uint16_t*)(ws + 19404288);           //  2,752,512
    uint16_t* WPb = (uint16_t*)(ws + 22156800);           //    917,504
    uint16_t* W1b = (uint16_t*)(ws + 23074304);           //  1,835,008
    uint16_t* W2b = (uint16_t*)(ws + 24909312);           //  1,835,008
    // X3 (104,633,856 B) aliases TOK..VT region — dead until after conv1m
    uint16_t* X3  = (uint16_t*)(ws + 26744320);
    float*    TOK = (float*)(ws + 26744320);              // 51,380,224 [b][h][w][c]
    float*    Z   = (float*)(ws + 78124544);              // 12,845,056
    uint16_t* Gbf = (uint16_t*)(ws + 90969600);           // 19,267,584
    uint16_t* Obf = (uint16_t*)(ws + 110237184);          //  6,422,528
    uint16_t* MLPb= (uint16_t*)(ws + 116659712);          // 12,845,056
    uint16_t* VT  = (uint16_t*)(ws + 129504768);          //  6,422,528
    // W2I/W1F: after X3's end (131,378,176), inside VT tail — VT only written by the
    // transformer layers, long after conv1/conv2 have consumed these.
    uint8_t*  W2I = (uint8_t*)(ws + 131378176);           //    301,056
    uint16_t* W1F = (uint16_t*)(ws + 131679232);          //     57,344
    // Tail scratch lives in the (dead-by-then) TOK region:
    float* LG   = (float*)(ws + 26744320);                //     50,176
    float* MU   = (float*)(ws + 26794496);                //     50,176
    float* RSW  = (float*)(ws + 26844672);                //     50,176
    float* SB   = (float*)(ws + 26894848);                //         64
    float* ACCP = (float*)(ws + 26894912);                //    200,704

    k_prep<<<14875, 256, 0, stream>>>(qkvw, projw, fc1w, fc2w, w1, w2, w3,
                                      WQb, WPb, W1b, W2b, W1B, WP2, WN2, WP3, WN3,
                                      (uint32_t*)W2I, W1F);
    k_prepx<<<102182, 256, 0, stream>>>(x, (uint32_t*)X3);

    k_conv1m<<<dim3(224, 9, 4), 256, 0, stream>>>(X3, W1F, B1P);
    k_conv2m<<<dim3(224, 3, 4), 256, 0, stream>>>(B1P, W2I, B2P);
    k_conv3<<<2352, 256, 0, stream>>>(B2P, WP3, WN3, H3);
    k_tok<<<dim3(112, 4), 256, 0, stream>>>(H3, tokw, TOK);
    k_pool_z<<<12544, 256, 0, stream>>>(TOK, pos, Z);

    for (int l = 0; l < 7; l++) {
        k_gemm_ln<<<dim3(6, 98), 256, 0, stream>>>(Z, WQb + (long)l * 196608,
                                                   ln1s + l * 256, ln1b + l * 256,
                                                   qkvb + l * 768, Gbf, VT,
                                                   768, 0, 1);
        k_flash<<<dim3(49, 4, 4), 256, 0, stream>>>(Gbf, VT, Obf);
        k_gemm64<<<dim3(4, 98), 256, 0, stream>>>(Obf, WPb + (long)l * 65536,
                                                  projb + l * 256, Z,
                                                  12544, 256, 256);
        k_gemm_ln<<<dim3(4, 98), 256, 0, stream>>>(Z, W1b + (long)l * 131072,
                                                   ln2s + l * 256, ln2b + l * 256,
                                                   fc1b + l * 512, MLPb, nullptr,
                                                   512, 1, 0);
        k_gemm64<<<dim3(4, 98), 256, 0, stream>>>(MLPb, W2b + (long)l * 131072,
                                                  fc2b + l * 256, Z,
                                                  12544, 256, 512);
    }

    k_tail_rows<<<dim3(49, 4), 256, 0, stream>>>(Z, lnfs, lnfb, poolw, poolb,
                                                 LG, MU, RSW);
    k_tail_sm<<<4, 256, 0, stream>>>(LG, MU, RSW, SB);
    k_tail_gemv<<<dim3(49, 4), 256, 0, stream>>>(Z, RSW, ACCP);
    k_tail_head<<<4, 256, 0, stream>>>(ACCP, SB, lnfs, lnfb, headw, headb, out);
}